// Round 4
// baseline (455.472 us; speedup 1.0000x reference)
//
#include <hip/hip_runtime.h>

typedef unsigned short u16;
typedef __attribute__((ext_vector_type(8))) short bf16x8;
typedef __attribute__((ext_vector_type(4))) float f32x4;
typedef __attribute__((ext_vector_type(8))) unsigned short u16x8;

#define B_ 2
#define T_ 2048
#define C_ 2048
#define H_ 16
#define D_ 128
#define QKVW 6144  // 3*C

__device__ __forceinline__ u16 f2b(float f) {
  unsigned int x = __builtin_bit_cast(unsigned int, f);
  x += 0x7fffu + ((x >> 16) & 1u);   // round-to-nearest-even
  return (u16)(x >> 16);
}
__device__ __forceinline__ float b2f(u16 u) {
  unsigned int x = ((unsigned int)u) << 16;
  return __builtin_bit_cast(float, x);
}
__device__ __forceinline__ void gl_lds16(const void* g, void* l) {
  __builtin_amdgcn_global_load_lds((const __attribute__((address_space(1))) void*)g,
                                   (__attribute__((address_space(3))) void*)l, 16, 0, 0);
}

// ---------------- cast fp32 -> bf16 (8 elems/thread) ----------------
__global__ void castbf(const float* __restrict__ in, u16* __restrict__ out) {
  int i = blockIdx.x * 256 + threadIdx.x;
  f32x4 a = ((const f32x4*)in)[2 * i];
  f32x4 b = ((const f32x4*)in)[2 * i + 1];
  u16x8 o;
  o[0] = f2b(a[0]); o[1] = f2b(a[1]); o[2] = f2b(a[2]); o[3] = f2b(a[3]);
  o[4] = f2b(b[0]); o[5] = f2b(b[1]); o[6] = f2b(b[2]); o[7] = f2b(b[3]);
  ((u16x8*)out)[i] = o;
}

// ------------- cast + transpose: in [K][N] fp32 -> out [N][K] bf16 -------------
__global__ __launch_bounds__(256) void castT(const float* __restrict__ in,
                                             u16* __restrict__ out, int K, int N) {
  __shared__ __align__(16) u16 ld[64][72];
  const int nt = blockIdx.x * 64, kt = blockIdx.y * 64;
  const int tid = threadIdx.x;
#pragma unroll
  for (int s = 0; s < 4; ++s) {
    int idx = tid + s * 256;        // 0..1023
    int r = idx >> 4;               // k row 0..63
    int c = (idx & 15) * 4;         // n col
    f32x4 v = *(const f32x4*)(in + (size_t)(kt + r) * N + nt + c);
    ld[r][c] = f2b(v[0]); ld[r][c + 1] = f2b(v[1]);
    ld[r][c + 2] = f2b(v[2]); ld[r][c + 3] = f2b(v[3]);
  }
  __syncthreads();
#pragma unroll
  for (int s = 0; s < 2; ++s) {
    int idx = tid + s * 256;        // 0..511
    int n = idx >> 3;               // 0..63
    int c8 = (idx & 7) * 8;         // k offset
    u16x8 o;
#pragma unroll
    for (int j = 0; j < 8; ++j) o[j] = ld[c8 + j][n];
    *(u16x8*)(out + (size_t)(nt + n) * K + kt + c8) = o;
  }
}

// ---------------- 128x256 BK=32 GEMM, 2 blocks/CU ----------------
// R4: occupancy fix. R3 post-mortem: conflicts 0, HBM 22%, VALU 16%, but
// MfmaUtil 33% — 128KB LDS + 244 unified regs/wave = 1 block/CU, and grid
// 384 = 1.5 rounds of 256 CUs (75% quantization). This kernel: per-wave
// 64x64 (acc 64 regs, total <=128 -> 4 waves/SIMD), LDS 48KB dbuf -> 2
// blocks/CU co-resident; cross-block overlap hides barrier/vmcnt drains.
// Quad-split LDS layout: per K-slice quad q, subtile [rows][16B], so every
// ds_read_b128 (16 lanes x consecutive 16B) and every gl_lds dest (64
// lanes contiguous 1KB) is conflict-free with NO swizzle arithmetic.
//   A buf: u16[4096]:  idx = q*1024 + half*512 + pr*8   (128 rows)
//   B buf: u16[8192]:  idx = 4096-rel: q*2048 + half*1024 + pr*8 (256 rows)
//   row = (pr>>5)*64 + half*32 + (pr&31)   (half = (row&63)>=32)
// 4-phase/K-tile schedule, counted vmcnt (A staged 3 phases ahead, B halves
// 2 ahead; never vmcnt(0) mid-loop):
//   P1: read a0,b0; issue A(t+1); vmcnt(1); bar; MFMA a0b0; bar
//   P2: read b1;    issue Bh0(t+1);          bar; MFMA a0b1; bar
//   P3: read a1;    issue Bh1(t+1);          bar; MFMA a1b1; bar
//   P4: MFMA a1b0; vmcnt(1); bar      (A,Bh0 of t+1 retired -> P1 safe)
template <int OUT_BF16>
__global__ __launch_bounds__(512, 4) void gemm128(const u16* __restrict__ A,
                                                  const u16* __restrict__ Bt,
                                                  void* __restrict__ Cout,
                                                  int M, int N, int K) {
  __shared__ __align__(16) u16 sm[2][12288];   // 48 KB total
  const int tid = threadIdx.x;
  const int lane = tid & 63, w = tid >> 6;
  const int quad = lane >> 4, l15 = lane & 15;
  const int wm = w >> 2, wn = w & 3;           // 2 x 4 waves, per-wave 64x64
  const int NXT = N >> 8;
  int id = blockIdx.x;
  const int cpx = gridDim.x >> 3;              // grid % 8 == 0 (768 / 256)
  id = (id & 7) * cpx + (id >> 3);             // XCD-contiguous chunks
  const int tn0 = (id % NXT) * 256, tm0 = (id / NXT) * 128;
  const int NT = K >> 5;                       // BK=32
  const u16* Ag = A + (size_t)tm0 * K;
  const u16* Bg = Bt + (size_t)tn0 * K;

  f32x4 acc[4][4] = {};
  bf16x8 a0[2], a1[2], b0[2], b1[2];

  // staging address precompute (per thread)
  const int aq = tid >> 7, aidx = tid & 127;
  const int ahalf = aidx >> 6, apr = aidx & 63;
  const int arow = (apr >> 5) * 64 + ahalf * 32 + (apr & 31);
  const int bq = tid >> 7, bpr = tid & 127;
  const int brow0 = (bpr >> 5) * 64 + (bpr & 31);   // + half*32

  auto stA = [&](int t) {
    gl_lds16(Ag + (size_t)arow * K + t * 32 + aq * 8, &sm[t & 1][tid * 8]);
  };
  auto stB = [&](int t, int half) {
    gl_lds16(Bg + (size_t)(brow0 + half * 32) * K + t * 32 + bq * 8,
             &sm[t & 1][4096 + bq * 2048 + half * 1024 + bpr * 8]);
  };

  // prologue: A(0), Bh0(0), Bh1(0); retire first two, keep Bh1 in flight
  stA(0); stB(0, 0); stB(0, 1);
  asm volatile("s_waitcnt vmcnt(1)" ::: "memory");
  __builtin_amdgcn_s_barrier();

  for (int t = 0; t < NT; ++t) {
    const u16* L = &sm[t & 1][0];
    // ---- P1: read a0,b0; issue A(t+1); MFMA a0xb0 ----
#pragma unroll
    for (int mi = 0; mi < 2; ++mi)
      a0[mi] = *(const bf16x8*)&L[quad * 1024 + (wm * 32 + mi * 16 + l15) * 8];
#pragma unroll
    for (int nj = 0; nj < 2; ++nj)
      b0[nj] = *(const bf16x8*)&L[4096 + quad * 2048 + (wn * 32 + nj * 16 + l15) * 8];
    if (t + 1 < NT) {
      stA(t + 1);
      asm volatile("s_waitcnt vmcnt(1)" ::: "memory");   // Bh1(t) retired
    } else {
      asm volatile("s_waitcnt vmcnt(0)" ::: "memory");
    }
    __builtin_amdgcn_s_barrier();
    asm volatile("s_waitcnt lgkmcnt(0)");
    __builtin_amdgcn_sched_barrier(0);
    __builtin_amdgcn_s_setprio(1);
#pragma unroll
    for (int mi = 0; mi < 2; ++mi)
#pragma unroll
      for (int nj = 0; nj < 2; ++nj)
        acc[mi][nj] = __builtin_amdgcn_mfma_f32_16x16x32_bf16(a0[mi], b0[nj], acc[mi][nj], 0, 0, 0);
    __builtin_amdgcn_s_setprio(0);
    __builtin_amdgcn_s_barrier();
    // ---- P2: read b1; issue Bh0(t+1); MFMA a0xb1 ----
#pragma unroll
    for (int nj = 0; nj < 2; ++nj)
      b1[nj] = *(const bf16x8*)&L[4096 + quad * 2048 + 1024 + (wn * 32 + nj * 16 + l15) * 8];
    if (t + 1 < NT) stB(t + 1, 0);
    __builtin_amdgcn_s_barrier();
    asm volatile("s_waitcnt lgkmcnt(0)");
    __builtin_amdgcn_sched_barrier(0);
    __builtin_amdgcn_s_setprio(1);
#pragma unroll
    for (int mi = 0; mi < 2; ++mi)
#pragma unroll
      for (int nj = 0; nj < 2; ++nj)
        acc[mi][nj + 2] = __builtin_amdgcn_mfma_f32_16x16x32_bf16(a0[mi], b1[nj], acc[mi][nj + 2], 0, 0, 0);
    __builtin_amdgcn_s_setprio(0);
    __builtin_amdgcn_s_barrier();
    // ---- P3: read a1; issue Bh1(t+1); MFMA a1xb1 ----
#pragma unroll
    for (int mi = 0; mi < 2; ++mi)
      a1[mi] = *(const bf16x8*)&L[quad * 1024 + 512 + (wm * 32 + mi * 16 + l15) * 8];
    if (t + 1 < NT) stB(t + 1, 1);
    __builtin_amdgcn_s_barrier();
    asm volatile("s_waitcnt lgkmcnt(0)");
    __builtin_amdgcn_sched_barrier(0);
    __builtin_amdgcn_s_setprio(1);
#pragma unroll
    for (int mi = 0; mi < 2; ++mi)
#pragma unroll
      for (int nj = 0; nj < 2; ++nj)
        acc[mi + 2][nj + 2] = __builtin_amdgcn_mfma_f32_16x16x32_bf16(a1[mi], b1[nj], acc[mi + 2][nj + 2], 0, 0, 0);
    __builtin_amdgcn_s_setprio(0);
    __builtin_amdgcn_s_barrier();
    // ---- P4: MFMA a1xb0; counted vmcnt; barrier -> next P1 safe ----
    __builtin_amdgcn_s_setprio(1);
#pragma unroll
    for (int mi = 0; mi < 2; ++mi)
#pragma unroll
      for (int nj = 0; nj < 2; ++nj)
        acc[mi + 2][nj] = __builtin_amdgcn_mfma_f32_16x16x32_bf16(a1[mi], b0[nj], acc[mi + 2][nj], 0, 0, 0);
    __builtin_amdgcn_s_setprio(0);
    if (t + 1 < NT)
      asm volatile("s_waitcnt vmcnt(1)" ::: "memory");   // A(t+1), Bh0(t+1) retired
    __builtin_amdgcn_s_barrier();
  }

  // epilogue: C/D layout col=lane&15, row=quad*4+reg
#pragma unroll
  for (int mi = 0; mi < 4; ++mi)
#pragma unroll
    for (int nj = 0; nj < 4; ++nj)
#pragma unroll
      for (int r = 0; r < 4; ++r) {
        int row = tm0 + wm * 64 + mi * 16 + quad * 4 + r;
        int col = tn0 + wn * 64 + nj * 16 + l15;
        float v = acc[mi][nj][r];
        if (OUT_BF16) ((u16*)Cout)[(size_t)row * N + col] = f2b(v);
        else          ((float*)Cout)[(size_t)row * N + col] = v;
      }
}

// ---------------- RoPE in-place on q,k of qkv (bf16) ----------------
__global__ void rope_k(u16* __restrict__ qkv) {
  int idx = blockIdx.x * 256 + threadIdx.x;   // 0 .. 2^23-1
  int i = idx & 63;
  int h = (idx >> 6) & 15;
  int which = (idx >> 10) & 1;
  int t = (idx >> 11) & 2047;
  int b = idx >> 22;
  size_t base = (size_t)(b * T_ + t) * QKVW + which * 2048 + h * 128 + i;
  float t1 = b2f(qkv[base]), t2 = b2f(qkv[base + 64]);
  // div_i = 10000^(-i/64) ; log2(10000)/64 = 0.20762050593046439
  float ang = (float)t * exp2f(-(float)i * 0.20762050593046439f);
  float sn, cs;
  sincosf(ang, &sn, &cs);
  qkv[base]      = f2b(t1 * cs - t2 * sn);
  qkv[base + 64] = f2b(t2 * cs + t1 * sn);
}

// ---------------- transpose V -> Vt [B*H][D][T] (bf16) ----------------
__global__ __launch_bounds__(256) void vtrans(const u16* __restrict__ qkv, u16* __restrict__ vt) {
  __shared__ __align__(16) u16 ld[128][136];
  const int tt = blockIdx.x, bh = blockIdx.y;
  const int b = bh >> 4, h = bh & 15;
  const u16* vb = qkv + (size_t)b * T_ * QKVW + 4096 + h * 128;
  const int tid = threadIdx.x;
#pragma unroll
  for (int s = 0; s < 8; ++s) {
    int t = (tid >> 4) + s * 16;
    int d0 = (tid & 15) * 8;
    *(bf16x8*)&ld[t][d0] = *(const bf16x8*)(vb + (size_t)(tt * 128 + t) * QKVW + d0);
  }
  __syncthreads();
  u16* vout = vt + (size_t)bh * D_ * T_ + tt * 128;
#pragma unroll
  for (int s = 0; s < 8; ++s) {
    int d = (tid >> 4) + s * 16;
    int t0 = (tid & 15) * 8;
    u16x8 o;
#pragma unroll
    for (int j = 0; j < 8; ++j) o[j] = ld[t0 + j][d];
    *(u16x8*)(vout + (size_t)d * T_ + t0) = o;
  }
}

// ---------------- flash attention (causal, online softmax) ----------------
// R3 structure (kept): causal-paired blocks (jA=jp, jB=31-jp, 33 units each),
// gl_lds staging w/ 3-bit XOR swizzle, K/V dbuf, per-lane partial l-sum
// (single epilogue reduce), ballot-gated defer-max (T13), T5 setprio.
// NOTE reference gotcha: out = einsum('bhts,bshd->bhtd').reshape(B,T,C) is a
// FLAT reshape of (B,H,T,D): element (b,h,t,d) sits at ((b*H+h)*T+t)*D+d.
#define APW 72    // P tile row stride (u16)
__global__ __launch_bounds__(256, 2) void attn(const u16* __restrict__ qkv,
                                               const u16* __restrict__ vt,
                                               u16* __restrict__ obuf) {
  __shared__ __align__(16) u16 lK[2][64 * 128];    // 2 x 16 KB, swizzled
  __shared__ __align__(16) u16 lV[2][128 * 64];    // 2 x 16 KB, swizzled
  __shared__ __align__(16) u16 lP[64 * APW];       // 9 KB, wave-private rows
  const int tid = threadIdx.x, lane = tid & 63, w = tid >> 6;
  const int quad = lane >> 4, l15 = lane & 15;
  const int bh = blockIdx.x, jp = blockIdx.y;
  const int jA = jp, jB = 31 - jp;                 // jA in 0..15, jB in 16..31
  const int b = bh >> 4, h = bh & 15;
  const u16* qb = qkv + (size_t)b * T_ * QKVW + h * 128;
  const u16* kb = qb + 2048;
  const u16* vtb = vt + (size_t)bh * D_ * T_;

  bf16x8 qfA[4], qfB[4];
#pragma unroll
  for (int kk = 0; kk < 4; ++kk) {
    qfA[kk] = *(const bf16x8*)(qb + (size_t)(jA * 64 + w * 16 + l15) * QKVW + kk * 32 + quad * 8);
    qfB[kk] = *(const bf16x8*)(qb + (size_t)(jB * 64 + w * 16 + l15) * QKVW + kk * 32 + quad * 8);
  }

  f32x4 oA[8] = {}, oB[8] = {};
  float mA[4], lAr[4], mB[4], lBr[4];
#pragma unroll
  for (int r = 0; r < 4; ++r) {
    mA[r] = -__builtin_inff(); lAr[r] = 0.f;
    mB[r] = -__builtin_inff(); lBr[r] = 0.f;
  }
  const float sc = 0.08838834764831845f * 1.4426950408889634f;  // 1/sqrt(128) * log2(e)

  auto stage = [&](int kt, int buf) {
#pragma unroll
    for (int s = 0; s < 4; ++s) {
      int ch = tid + s * 256;                        // 0..1023
      int kr = ch >> 4, kc = (ch & 15) ^ (kr & 7);   // K row 0..63, 16 chunks/row
      gl_lds16(kb + (size_t)(kt * 64 + kr) * QKVW + kc * 8, &lK[buf][ch * 8]);
      int vr = ch >> 3, vc = (ch & 7) ^ (vr & 7);    // V row 0..127, 8 chunks/row
      gl_lds16(vtb + (size_t)vr * T_ + kt * 64 + vc * 8, &lV[buf][ch * 8]);
    }
  };

  auto tile_compute = [&](const bf16x8* qf, f32x4* oacc, float* mrow, float* lrow,
                          int jw, int kt, int cb) {
    // S = Q K^T   (16 q-rows x 64 keys per wave)
    f32x4 sacc[4] = {};
#pragma unroll
    for (int kk = 0; kk < 4; ++kk) {
      bf16x8 kf[4];
#pragma unroll
      for (int nj = 0; nj < 4; ++nj) {
        int r = nj * 16 + l15;
        kf[nj] = *(const bf16x8*)&lK[cb][r * 128 + ((kk * 32 + quad * 8) ^ ((r & 7) << 3))];
      }
      __builtin_amdgcn_s_setprio(1);
#pragma unroll
      for (int nj = 0; nj < 4; ++nj)
        sacc[nj] = __builtin_amdgcn_mfma_f32_16x16x32_bf16(qf[kk], kf[nj], sacc[nj], 0, 0, 0);
      __builtin_amdgcn_s_setprio(0);
    }
    const bool diag = (kt == jw);
#pragma unroll
    for (int nj = 0; nj < 4; ++nj) {
      int key = nj * 16 + l15;                 // local key 0..63
#pragma unroll
      for (int r = 0; r < 4; ++r) {
        float s = sacc[nj][r] * sc;
        if (diag) {
          int qrow = w * 16 + quad * 4 + r;    // local q 0..63
          if (key > qrow) s = -__builtin_inff();
        }
        sacc[nj][r] = s;
      }
    }
    // per-lane partial max + single ballot defer-check (T13)
    float pm[4];
#pragma unroll
    for (int r = 0; r < 4; ++r)
      pm[r] = fmaxf(fmaxf(sacc[0][r], sacc[1][r]), fmaxf(sacc[2][r], sacc[3][r]));
    float dmax = fmaxf(fmaxf(pm[0] - mrow[0], pm[1] - mrow[1]),
                       fmaxf(pm[2] - mrow[2], pm[3] - mrow[3]));
    if (__any(dmax > 11.5f)) {                 // rare: real max growth
#pragma unroll
      for (int r = 0; r < 4; ++r) {
        float rm = pm[r];
        rm = fmaxf(rm, __shfl_xor(rm, 1));
        rm = fmaxf(rm, __shfl_xor(rm, 2));
        rm = fmaxf(rm, __shfl_xor(rm, 4));
        rm = fmaxf(rm, __shfl_xor(rm, 8));
        float mold = mrow[r];
        float mnew = fmaxf(mold, rm);
        float alpha = exp2f(mold - mnew);
#pragma unroll
        for (int nd = 0; nd < 8; ++nd) oacc[nd][r] *= alpha;
        lrow[r] *= alpha;
        mrow[r] = mnew;
      }
    }
#pragma unroll
    for (int r = 0; r < 4; ++r) {
      int prow = w * 16 + quad * 4 + r;        // wave-private P row
      float rs = 0.f;
#pragma unroll
      for (int nj = 0; nj < 4; ++nj) {
        float p = exp2f(sacc[nj][r] - mrow[r]);
        rs += p;
        lP[prow * APW + nj * 16 + l15] = f2b(p);
      }
      lrow[r] += rs;                           // PER-LANE partial (no shfl!)
    }
    // PV: O += P * V  (P rows wave-private — no barrier needed)
#pragma unroll
    for (int kk = 0; kk < 2; ++kk) {
      bf16x8 pf, vf[8];
      pf = *(const bf16x8*)&lP[(w * 16 + l15) * APW + kk * 32 + quad * 8];
#pragma unroll
      for (int nd = 0; nd < 8; ++nd) {
        int r = nd * 16 + l15;
        vf[nd] = *(const bf16x8*)&lV[cb][r * 64 + ((kk * 32 + quad * 8) ^ ((r & 7) << 3))];
      }
      __builtin_amdgcn_s_setprio(1);
#pragma unroll
      for (int nd = 0; nd < 8; ++nd)
        oacc[nd] = __builtin_amdgcn_mfma_f32_16x16x32_bf16(pf, vf[nd], oacc[nd], 0, 0, 0);
      __builtin_amdgcn_s_setprio(0);
    }
  };

  stage(0, 0);
  __syncthreads();   // drains vmcnt (implicit in __syncthreads)

  for (int kt = 0; kt <= jB; ++kt) {
    int cb = kt & 1;
    if (kt < jB) stage(kt + 1, cb ^ 1);       // overlap next-tile DMA with compute
    tile_compute(qfB, oB, mB, lBr, jB, kt, cb);
    if (kt <= jA) tile_compute(qfA, oA, mA, lAr, jA, kt, cb);
    __syncthreads();                          // drains stage DMA + LDS, swap bufs
  }

  // single cross-lane reduction of the per-lane l partials
#pragma unroll
  for (int r = 0; r < 4; ++r) {
    float sA = lAr[r], sB = lBr[r];
    sA += __shfl_xor(sA, 1); sB += __shfl_xor(sB, 1);
    sA += __shfl_xor(sA, 2); sB += __shfl_xor(sB, 2);
    sA += __shfl_xor(sA, 4); sB += __shfl_xor(sB, 4);
    sA += __shfl_xor(sA, 8); sB += __shfl_xor(sB, 8);
    lAr[r] = sA; lBr[r] = sB;
  }

  // epilogue: O / l -> bf16, REFERENCE-MATCHED layout [B*H][T][D] (see note)
#pragma unroll
  for (int nd = 0; nd < 8; ++nd)
#pragma unroll
    for (int r = 0; r < 4; ++r) {
      int dcol = nd * 16 + l15;
      int qrB = jB * 64 + w * 16 + quad * 4 + r;
      obuf[((size_t)bh * T_ + qrB) * D_ + dcol] = f2b(oB[nd][r] / lBr[r]);
      int qrA = jA * 64 + w * 16 + quad * 4 + r;
      obuf[((size_t)bh * T_ + qrA) * D_ + dcol] = f2b(oA[nd][r] / lAr[r]);
    }
}

extern "C" void kernel_launch(void* const* d_in, const int* in_sizes, int n_in,
                              void* d_out, int out_size, void* d_ws, size_t ws_size,
                              hipStream_t stream) {
  const float* x = (const float*)d_in[0];
  const float* Wqkv = (const float*)d_in[1];
  const float* Wout = (const float*)d_in[2];
  float* out = (float*)d_out;
  char* ws = (char*)d_ws;

  // workspace layout (bytes):
  //   [0,            16777216)  xb (x bf16)   -- later reused as Ob (attn out bf16)
  //   [16777216,     41943040)  Wqkv_t bf16   -- later reused as Wout_t bf16
  //   [41943040,     92274688)  qkv bf16 [4096][6144]
  //   [92274688,    109051904)  Vt bf16 [B*H][128][2048]
  u16* xb   = (u16*)ws;
  u16* wqt  = (u16*)(ws + 16777216);
  u16* qkvb = (u16*)(ws + 41943040);
  u16* vtb  = (u16*)(ws + 92274688);
  u16* wot  = wqt;   // alias: cast after GEMM1 consumed Wqkv_t
  u16* ob   = xb;    // alias: attn output after GEMM1 consumed xb

  castbf<<<4096, 256, 0, stream>>>(x, xb);                                  // 8.4M elems
  castT<<<dim3(96, 32), 256, 0, stream>>>(Wqkv, wqt, 2048, 6144);
  gemm128<1><<<dim3(768), 512, 0, stream>>>(xb, wqt, qkvb, 4096, 6144, 2048);
  castT<<<dim3(32, 32), 256, 0, stream>>>(Wout, wot, 2048, 2048);
  rope_k<<<32768, 256, 0, stream>>>(qkvb);
  vtrans<<<dim3(16, 32), 256, 0, stream>>>(qkvb, vtb);
  attn<<<dim3(32, 16), 256, 0, stream>>>(qkvb, vtb, ob);   // (bh, jpair)
  gemm128<0><<<dim3(256), 512, 0, stream>>>(ob, wot, out, 4096, 2048, 2048);
}

// Round 5
// 400.715 us; speedup vs baseline: 1.1366x; 1.1366x over previous
//
#include <hip/hip_runtime.h>

typedef unsigned short u16;
typedef __attribute__((ext_vector_type(8))) short bf16x8;
typedef __attribute__((ext_vector_type(4))) float f32x4;
typedef __attribute__((ext_vector_type(8))) unsigned short u16x8;

#define B_ 2
#define T_ 2048
#define C_ 2048
#define H_ 16
#define D_ 128
#define QKVW 6144  // 3*C

__device__ __forceinline__ u16 f2b(float f) {
  unsigned int x = __builtin_bit_cast(unsigned int, f);
  x += 0x7fffu + ((x >> 16) & 1u);   // round-to-nearest-even
  return (u16)(x >> 16);
}
__device__ __forceinline__ float b2f(u16 u) {
  unsigned int x = ((unsigned int)u) << 16;
  return __builtin_bit_cast(float, x);
}
__device__ __forceinline__ void gl_lds16(const void* g, void* l) {
  __builtin_amdgcn_global_load_lds((const __attribute__((address_space(1))) void*)g,
                                   (__attribute__((address_space(3))) void*)l, 16, 0, 0);
}

// ---------------- cast fp32 -> bf16 (8 elems/thread) ----------------
__global__ void castbf(const float* __restrict__ in, u16* __restrict__ out) {
  int i = blockIdx.x * 256 + threadIdx.x;
  f32x4 a = ((const f32x4*)in)[2 * i];
  f32x4 b = ((const f32x4*)in)[2 * i + 1];
  u16x8 o;
  o[0] = f2b(a[0]); o[1] = f2b(a[1]); o[2] = f2b(a[2]); o[3] = f2b(a[3]);
  o[4] = f2b(b[0]); o[5] = f2b(b[1]); o[6] = f2b(b[2]); o[7] = f2b(b[3]);
  ((u16x8*)out)[i] = o;
}

// ------------- cast + transpose: in [K][N] fp32 -> out [N][K] bf16 -------------
__global__ __launch_bounds__(256) void castT(const float* __restrict__ in,
                                             u16* __restrict__ out, int K, int N) {
  __shared__ __align__(16) u16 ld[64][72];
  const int nt = blockIdx.x * 64, kt = blockIdx.y * 64;
  const int tid = threadIdx.x;
#pragma unroll
  for (int s = 0; s < 4; ++s) {
    int idx = tid + s * 256;        // 0..1023
    int r = idx >> 4;               // k row 0..63
    int c = (idx & 15) * 4;         // n col
    f32x4 v = *(const f32x4*)(in + (size_t)(kt + r) * N + nt + c);
    ld[r][c] = f2b(v[0]); ld[r][c + 1] = f2b(v[1]);
    ld[r][c + 2] = f2b(v[2]); ld[r][c + 3] = f2b(v[3]);
  }
  __syncthreads();
#pragma unroll
  for (int s = 0; s < 2; ++s) {
    int idx = tid + s * 256;        // 0..511
    int n = idx >> 3;               // 0..63
    int c8 = (idx & 7) * 8;         // k offset
    u16x8 o;
#pragma unroll
    for (int j = 0; j < 8; ++j) o[j] = ld[c8 + j][n];
    *(u16x8*)(out + (size_t)(nt + n) * K + kt + c8) = o;
  }
}

// ---------------- 256x256 8-phase GEMM (m201-style), bf16 MFMA ----------------
// R5: REVERTED to the R3 kernel (127us, MfmaUtil 33.6%, conflicts 0).
// R4's 128x256 BK=32 experiment regressed (24% util): 4-MFMA phases are
// barrier-dominated — phase granularity must stay >=16 MFMA.
// Full 3-bit G4 swizzle (chunk ^= row&7); linear LDS dest (global_load_lds)
// + pre-swizzled SOURCE + swizzled read (rule #21).
__device__ __forceinline__ void stage_chunk(const u16* __restrict__ g, int K,
                                            u16* l, int ch) {
  int row = ch >> 3;
  int c = (ch & 7) ^ (row & 7);                 // inverse swizzle on source
  gl_lds16(g + (size_t)row * K + c * 8, l + ch * 8);
}

#define MFMA_Q(AF, BF, MH, NH)                                               \
  _Pragma("unroll")                                                          \
  for (int mi = 0; mi < 4; ++mi) {                                           \
    _Pragma("unroll")                                                        \
    for (int ni = 0; ni < 2; ++ni) {                                         \
      _Pragma("unroll")                                                      \
      for (int ks = 0; ks < 2; ++ks)                                         \
        acc[(MH)*4 + mi][(NH)*2 + ni] =                                      \
            __builtin_amdgcn_mfma_f32_16x16x32_bf16(                         \
                AF[mi][ks], BF[ni][ks], acc[(MH)*4 + mi][(NH)*2 + ni],       \
                0, 0, 0);                                                    \
    }                                                                        \
  }

template <int OUT_BF16>
__global__ __launch_bounds__(512, 2) void gemm256(const u16* __restrict__ A,
                                                  const u16* __restrict__ Bt,
                                                  void* __restrict__ Cout,
                                                  int M, int N, int K) {
  __shared__ __align__(16) u16 sm[65536];   // 128 KiB: 2 bufs x (A 32KB | B 32KB)
  const int tid = threadIdx.x;
  const int lane = tid & 63, w = tid >> 6;
  const int quad = lane >> 4, l15 = lane & 15;
  const int wm = w >> 2, wn = w & 3;        // 2 x 4 wave grid, per-wave C 128x64
  const int NXT = N >> 8;
  int id = blockIdx.x;
  const int cpx = gridDim.x >> 3;           // grid % 8 == 0 (384 / 128)
  id = (id & 7) * cpx + (id >> 3);          // XCD-contiguous chunks
  const int tn0 = (id % NXT) * 256, tm0 = (id / NXT) * 256;
  const int NT = K >> 6;
  const u16* Ag = A + (size_t)tm0 * K;
  const u16* Bg = Bt + (size_t)tn0 * K;

  f32x4 acc[8][4] = {};
  bf16x8 a0[4][2], a1[4][2], b0[2][2], b1[2][2];

  auto stA = [&](int tt, int half) {        // half 0 -> U1, 1 -> U3
    u16* l = &sm[(tt & 1) * 32768];
    const u16* g = Ag + tt * 64;
    stage_chunk(g, K, l, half * 512 + tid);
    stage_chunk(g, K, l, 1024 + half * 512 + tid);
  };
  auto stB = [&](int tt, int nh) {          // nh 0 -> U2, 1 -> U4
    u16* l = &sm[(tt & 1) * 32768 + 16384];
    const u16* g = Bg + tt * 64;
    int ch = nh * 256 + (tid & 255) + ((tid >> 8) << 9);
    stage_chunk(g, K, l, ch);
    stage_chunk(g, K, l, ch + 1024);
  };

  // prologue: T0.U1-U4, T1.U1-U3 (7 units in flight), retire T0, keep 3
  stA(0, 0); stB(0, 0); stA(0, 1); stB(0, 1);
  if (NT > 1) {
    stA(1, 0); stB(1, 0); stA(1, 1);
    asm volatile("s_waitcnt vmcnt(6)" ::: "memory");
  } else {
    asm volatile("s_waitcnt vmcnt(0)" ::: "memory");
  }
  __builtin_amdgcn_s_barrier();

  for (int t = 0; t < NT; ++t) {
    const u16* LA = &sm[(t & 1) * 32768];
    const u16* LB = LA + 16384;
    // ---- P1: read a0 (8) + b0 (4); stage (t+1).U4; MFMA Q1 ----
#pragma unroll
    for (int mi = 0; mi < 4; ++mi)
#pragma unroll
      for (int ks = 0; ks < 2; ++ks) {
        int r = wm * 128 + mi * 16 + l15;
        a0[mi][ks] = *(const bf16x8*)&LA[r * 64 +
                     ((ks * 32 + quad * 8) ^ ((r & 7) << 3))];
      }
#pragma unroll
    for (int ni = 0; ni < 2; ++ni)
#pragma unroll
      for (int ks = 0; ks < 2; ++ks) {
        int r = wn * 64 + ni * 16 + l15;
        b0[ni][ks] = *(const bf16x8*)&LB[r * 64 +
                     ((ks * 32 + quad * 8) ^ ((r & 7) << 3))];
      }
    if (t + 1 < NT) stB(t + 1, 1);
    __builtin_amdgcn_s_barrier();
    asm volatile("s_waitcnt lgkmcnt(0)");
    __builtin_amdgcn_sched_barrier(0);
    __builtin_amdgcn_s_setprio(1);
    MFMA_Q(a0, b0, 0, 0);
    __builtin_amdgcn_s_setprio(0);
    __builtin_amdgcn_s_barrier();
    // ---- P2: read b1 (4); stage (t+2).U1; MFMA Q2 ----
#pragma unroll
    for (int ni = 0; ni < 2; ++ni)
#pragma unroll
      for (int ks = 0; ks < 2; ++ks) {
        int r = wn * 64 + (ni + 2) * 16 + l15;
        b1[ni][ks] = *(const bf16x8*)&LB[r * 64 +
                     ((ks * 32 + quad * 8) ^ ((r & 7) << 3))];
      }
    if (t + 2 < NT) stA(t + 2, 0);
    __builtin_amdgcn_s_barrier();
    asm volatile("s_waitcnt lgkmcnt(0)");
    __builtin_amdgcn_sched_barrier(0);
    __builtin_amdgcn_s_setprio(1);
    MFMA_Q(a0, b1, 0, 1);
    __builtin_amdgcn_s_setprio(0);
    __builtin_amdgcn_s_barrier();
    // ---- P3: read a1 (8); stage (t+2).U2; MFMA Q3 ----
#pragma unroll
    for (int mi = 0; mi < 4; ++mi)
#pragma unroll
      for (int ks = 0; ks < 2; ++ks) {
        int r = wm * 128 + (mi + 4) * 16 + l15;
        a1[mi][ks] = *(const bf16x8*)&LA[r * 64 +
                     ((ks * 32 + quad * 8) ^ ((r & 7) << 3))];
      }
    if (t + 2 < NT) stB(t + 2, 0);
    __builtin_amdgcn_s_barrier();
    asm volatile("s_waitcnt lgkmcnt(0)");
    __builtin_amdgcn_sched_barrier(0);
    __builtin_amdgcn_s_setprio(1);
    MFMA_Q(a1, b1, 1, 1);
    __builtin_amdgcn_s_setprio(0);
    __builtin_amdgcn_s_barrier();
    // ---- P4: stage (t+2).U3; counted vmcnt; MFMA Q4 ----
    if (t + 2 < NT) {
      stA(t + 2, 1);
      asm volatile("s_waitcnt vmcnt(6)" ::: "memory");
    } else {
      asm volatile("s_waitcnt vmcnt(0)" ::: "memory");
    }
    __builtin_amdgcn_s_barrier();
    __builtin_amdgcn_s_setprio(1);
    MFMA_Q(a1, b0, 1, 0);
    __builtin_amdgcn_s_setprio(0);
    __builtin_amdgcn_s_barrier();
  }

  // epilogue: C/D layout col=lane&15, row=quad*4+reg
#pragma unroll
  for (int mi = 0; mi < 8; ++mi)
#pragma unroll
    for (int ni = 0; ni < 4; ++ni)
#pragma unroll
      for (int r = 0; r < 4; ++r) {
        int row = tm0 + wm * 128 + mi * 16 + quad * 4 + r;
        int col = tn0 + wn * 64 + ni * 16 + l15;
        float v = acc[mi][ni][r];
        if (OUT_BF16) ((u16*)Cout)[(size_t)row * N + col] = f2b(v);
        else          ((float*)Cout)[(size_t)row * N + col] = v;
      }
}

// ---------------- RoPE in-place on q,k of qkv (bf16), vectorized x8 ----------------
// R5: G13 — was 2-byte scalar loads (8.4M threads); now u16x8 (16B/lane).
__global__ void rope_k(u16* __restrict__ qkv) {
  int g = blockIdx.x * 256 + threadIdx.x;     // 0 .. 2^20-1
  int i0 = (g & 7) * 8;                       // 8 consecutive i's
  int h = (g >> 3) & 15;
  int which = (g >> 7) & 1;
  int t = (g >> 8) & 2047;
  int b = g >> 19;
  size_t base = (size_t)(b * T_ + t) * QKVW + which * 2048 + h * 128 + i0;
  u16x8 v1 = *(const u16x8*)(qkv + base);
  u16x8 v2 = *(const u16x8*)(qkv + base + 64);
  u16x8 o1, o2;
#pragma unroll
  for (int j = 0; j < 8; ++j) {
    int i = i0 + j;
    float t1 = b2f(v1[j]), t2 = b2f(v2[j]);
    // div_i = 10000^(-i/64) ; log2(10000)/64 = 0.20762050593046439
    float ang = (float)t * exp2f(-(float)i * 0.20762050593046439f);
    float sn, cs;
    sincosf(ang, &sn, &cs);
    o1[j] = f2b(t1 * cs - t2 * sn);
    o2[j] = f2b(t2 * cs + t1 * sn);
  }
  *(u16x8*)(qkv + base) = o1;
  *(u16x8*)(qkv + base + 64) = o2;
}

// ---------------- transpose V -> Vt [B*H][D][T] (bf16) ----------------
__global__ __launch_bounds__(256) void vtrans(const u16* __restrict__ qkv, u16* __restrict__ vt) {
  __shared__ __align__(16) u16 ld[128][136];
  const int tt = blockIdx.x, bh = blockIdx.y;
  const int b = bh >> 4, h = bh & 15;
  const u16* vb = qkv + (size_t)b * T_ * QKVW + 4096 + h * 128;
  const int tid = threadIdx.x;
#pragma unroll
  for (int s = 0; s < 8; ++s) {
    int t = (tid >> 4) + s * 16;
    int d0 = (tid & 15) * 8;
    *(bf16x8*)&ld[t][d0] = *(const bf16x8*)(vb + (size_t)(tt * 128 + t) * QKVW + d0);
  }
  __syncthreads();
  u16* vout = vt + (size_t)bh * D_ * T_ + tt * 128;
#pragma unroll
  for (int s = 0; s < 8; ++s) {
    int d = (tid >> 4) + s * 16;
    int t0 = (tid & 15) * 8;
    u16x8 o;
#pragma unroll
    for (int j = 0; j < 8; ++j) o[j] = ld[t0 + j][d];
    *(u16x8*)(vout + (size_t)d * T_ + t0) = o;
  }
}

// ---------------- flash attention (causal, online softmax) ----------------
// R5: shared K-fragments across the causal pair. Paired iterations (kt<=jA)
// previously read the identical lK tile twice (16 b128 each); QK_B and QK_A
// now share one kf load loop — ~25% of total ds_read traffic removed.
// Kept from R3: causal pairing (jA=jp, jB=31-jp), gl_lds + 3-bit XOR swizzle,
// K/V dbuf, per-lane partial l-sum, ballot-gated defer-max, T5 setprio.
// NOTE reference gotcha: out = einsum('bhts,bshd->bhtd').reshape(B,T,C) is a
// FLAT reshape of (B,H,T,D): element (b,h,t,d) sits at ((b*H+h)*T+t)*D+d.
#define APW 72    // P tile row stride (u16)
__global__ __launch_bounds__(256, 2) void attn(const u16* __restrict__ qkv,
                                               const u16* __restrict__ vt,
                                               u16* __restrict__ obuf) {
  __shared__ __align__(16) u16 lK[2][64 * 128];    // 2 x 16 KB, swizzled
  __shared__ __align__(16) u16 lV[2][128 * 64];    // 2 x 16 KB, swizzled
  __shared__ __align__(16) u16 lP[64 * APW];       // 9 KB, wave-private rows
  const int tid = threadIdx.x, lane = tid & 63, w = tid >> 6;
  const int quad = lane >> 4, l15 = lane & 15;
  const int bh = blockIdx.x, jp = blockIdx.y;
  const int jA = jp, jB = 31 - jp;                 // jA in 0..15, jB in 16..31
  const int b = bh >> 4, h = bh & 15;
  const u16* qb = qkv + (size_t)b * T_ * QKVW + h * 128;
  const u16* kb = qb + 2048;
  const u16* vtb = vt + (size_t)bh * D_ * T_;

  bf16x8 qfA[4], qfB[4];
#pragma unroll
  for (int kk = 0; kk < 4; ++kk) {
    qfA[kk] = *(const bf16x8*)(qb + (size_t)(jA * 64 + w * 16 + l15) * QKVW + kk * 32 + quad * 8);
    qfB[kk] = *(const bf16x8*)(qb + (size_t)(jB * 64 + w * 16 + l15) * QKVW + kk * 32 + quad * 8);
  }

  f32x4 oA[8] = {}, oB[8] = {};
  float mA[4], lAr[4], mB[4], lBr[4];
#pragma unroll
  for (int r = 0; r < 4; ++r) {
    mA[r] = -__builtin_inff(); lAr[r] = 0.f;
    mB[r] = -__builtin_inff(); lBr[r] = 0.f;
  }
  const float sc = 0.08838834764831845f * 1.4426950408889634f;  // 1/sqrt(128) * log2(e)

  auto stage = [&](int kt, int buf) {
#pragma unroll
    for (int s = 0; s < 4; ++s) {
      int ch = tid + s * 256;                        // 0..1023
      int kr = ch >> 4, kc = (ch & 15) ^ (kr & 7);   // K row 0..63, 16 chunks/row
      gl_lds16(kb + (size_t)(kt * 64 + kr) * QKVW + kc * 8, &lK[buf][ch * 8]);
      int vr = ch >> 3, vc = (ch & 7) ^ (vr & 7);    // V row 0..127, 8 chunks/row
      gl_lds16(vtb + (size_t)vr * T_ + kt * 64 + vc * 8, &lV[buf][ch * 8]);
    }
  };

  // softmax + PV for one q-tile's S-accumulator (QK^T already done)
  auto smpv = [&](f32x4* sacc, f32x4* oacc, float* mrow, float* lrow,
                  int jw, int kt, int cb) {
    const bool diag = (kt == jw);
#pragma unroll
    for (int nj = 0; nj < 4; ++nj) {
      int key = nj * 16 + l15;                 // local key 0..63
#pragma unroll
      for (int r = 0; r < 4; ++r) {
        float s = sacc[nj][r] * sc;
        if (diag) {
          int qrow = w * 16 + quad * 4 + r;    // local q 0..63
          if (key > qrow) s = -__builtin_inff();
        }
        sacc[nj][r] = s;
      }
    }
    // per-lane partial max + single ballot defer-check (T13)
    float pm[4];
#pragma unroll
    for (int r = 0; r < 4; ++r)
      pm[r] = fmaxf(fmaxf(sacc[0][r], sacc[1][r]), fmaxf(sacc[2][r], sacc[3][r]));
    float dmax = fmaxf(fmaxf(pm[0] - mrow[0], pm[1] - mrow[1]),
                       fmaxf(pm[2] - mrow[2], pm[3] - mrow[3]));
    if (__any(dmax > 11.5f)) {                 // rare: real max growth
#pragma unroll
      for (int r = 0; r < 4; ++r) {
        float rm = pm[r];
        rm = fmaxf(rm, __shfl_xor(rm, 1));
        rm = fmaxf(rm, __shfl_xor(rm, 2));
        rm = fmaxf(rm, __shfl_xor(rm, 4));
        rm = fmaxf(rm, __shfl_xor(rm, 8));
        float mold = mrow[r];
        float mnew = fmaxf(mold, rm);
        float alpha = exp2f(mold - mnew);
#pragma unroll
        for (int nd = 0; nd < 8; ++nd) oacc[nd][r] *= alpha;
        lrow[r] *= alpha;
        mrow[r] = mnew;
      }
    }
#pragma unroll
    for (int r = 0; r < 4; ++r) {
      int prow = w * 16 + quad * 4 + r;        // wave-private P row
      float rs = 0.f;
#pragma unroll
      for (int nj = 0; nj < 4; ++nj) {
        float p = exp2f(sacc[nj][r] - mrow[r]);
        rs += p;
        lP[prow * APW + nj * 16 + l15] = f2b(p);
      }
      lrow[r] += rs;                           // per-lane partial (no shfl)
    }
    // PV: O += P * V  (P rows wave-private — no barrier needed)
#pragma unroll
    for (int kk = 0; kk < 2; ++kk) {
      bf16x8 pf, vf[8];
      pf = *(const bf16x8*)&lP[(w * 16 + l15) * APW + kk * 32 + quad * 8];
#pragma unroll
      for (int nd = 0; nd < 8; ++nd) {
        int r = nd * 16 + l15;
        vf[nd] = *(const bf16x8*)&lV[cb][r * 64 + ((kk * 32 + quad * 8) ^ ((r & 7) << 3))];
      }
      __builtin_amdgcn_s_setprio(1);
#pragma unroll
      for (int nd = 0; nd < 8; ++nd)
        oacc[nd] = __builtin_amdgcn_mfma_f32_16x16x32_bf16(pf, vf[nd], oacc[nd], 0, 0, 0);
      __builtin_amdgcn_s_setprio(0);
    }
  };

  stage(0, 0);
  __syncthreads();   // drains vmcnt (implicit in __syncthreads)

  for (int kt = 0; kt <= jB; ++kt) {
    int cb = kt & 1;
    if (kt < jB) stage(kt + 1, cb ^ 1);       // overlap next-tile DMA with compute
    const bool doA = (kt <= jA);
    // QK^T for B (and A when paired) with a SINGLE kf load per kk
    f32x4 sB[4] = {}, sA[4] = {};
#pragma unroll
    for (int kk = 0; kk < 4; ++kk) {
      bf16x8 kf[4];
#pragma unroll
      for (int nj = 0; nj < 4; ++nj) {
        int r = nj * 16 + l15;
        kf[nj] = *(const bf16x8*)&lK[cb][r * 128 + ((kk * 32 + quad * 8) ^ ((r & 7) << 3))];
      }
      __builtin_amdgcn_s_setprio(1);
#pragma unroll
      for (int nj = 0; nj < 4; ++nj)
        sB[nj] = __builtin_amdgcn_mfma_f32_16x16x32_bf16(qfB[kk], kf[nj], sB[nj], 0, 0, 0);
      if (doA)
#pragma unroll
        for (int nj = 0; nj < 4; ++nj)
          sA[nj] = __builtin_amdgcn_mfma_f32_16x16x32_bf16(qfA[kk], kf[nj], sA[nj], 0, 0, 0);
      __builtin_amdgcn_s_setprio(0);
    }
    smpv(sB, oB, mB, lBr, jB, kt, cb);
    if (doA) smpv(sA, oA, mA, lAr, jA, kt, cb);
    __syncthreads();                          // drains stage DMA + LDS, swap bufs
  }

  // single cross-lane reduction of the per-lane l partials
#pragma unroll
  for (int r = 0; r < 4; ++r) {
    float sA = lAr[r], sB = lBr[r];
    sA += __shfl_xor(sA, 1); sB += __shfl_xor(sB, 1);
    sA += __shfl_xor(sA, 2); sB += __shfl_xor(sB, 2);
    sA += __shfl_xor(sA, 4); sB += __shfl_xor(sB, 4);
    sA += __shfl_xor(sA, 8); sB += __shfl_xor(sB, 8);
    lAr[r] = sA; lBr[r] = sB;
  }

  // epilogue: O / l -> bf16, REFERENCE-MATCHED layout [B*H][T][D] (see note)
#pragma unroll
  for (int nd = 0; nd < 8; ++nd)
#pragma unroll
    for (int r = 0; r < 4; ++r) {
      int dcol = nd * 16 + l15;
      int qrB = jB * 64 + w * 16 + quad * 4 + r;
      obuf[((size_t)bh * T_ + qrB) * D_ + dcol] = f2b(oB[nd][r] / lBr[r]);
      int qrA = jA * 64 + w * 16 + quad * 4 + r;
      obuf[((size_t)bh * T_ + qrA) * D_ + dcol] = f2b(oA[nd][r] / lAr[r]);
    }
}

extern "C" void kernel_launch(void* const* d_in, const int* in_sizes, int n_in,
                              void* d_out, int out_size, void* d_ws, size_t ws_size,
                              hipStream_t stream) {
  const float* x = (const float*)d_in[0];
  const float* Wqkv = (const float*)d_in[1];
  const float* Wout = (const float*)d_in[2];
  float* out = (float*)d_out;
  char* ws = (char*)d_ws;

  // workspace layout (bytes):
  //   [0,            16777216)  xb (x bf16)   -- later reused as Ob (attn out bf16)
  //   [16777216,     41943040)  Wqkv_t bf16   -- later reused as Wout_t bf16
  //   [41943040,     92274688)  qkv bf16 [4096][6144]
  //   [92274688,    109051904)  Vt bf16 [B*H][128][2048]
  u16* xb   = (u16*)ws;
  u16* wqt  = (u16*)(ws + 16777216);
  u16* qkvb = (u16*)(ws + 41943040);
  u16* vtb  = (u16*)(ws + 92274688);
  u16* wot  = wqt;   // alias: cast after GEMM1 consumed Wqkv_t
  u16* ob   = xb;    // alias: attn output after GEMM1 consumed xb

  castbf<<<4096, 256, 0, stream>>>(x, xb);                                  // 8.4M elems
  castT<<<dim3(96, 32), 256, 0, stream>>>(Wqkv, wqt, 2048, 6144);
  gemm256<1><<<dim3(384), 512, 0, stream>>>(xb, wqt, qkvb, 4096, 6144, 2048);
  castT<<<dim3(32, 32), 256, 0, stream>>>(Wout, wot, 2048, 2048);
  rope_k<<<4096, 256, 0, stream>>>(qkvb);
  vtrans<<<dim3(16, 32), 256, 0, stream>>>(qkvb, vtb);
  attn<<<dim3(32, 16), 256, 0, stream>>>(qkvb, vtb, ob);   // (bh, jpair)
  gemm256<0><<<dim3(128), 512, 0, stream>>>(ob, wot, out, 4096, 2048, 2048);
}

// Round 8
// 375.950 us; speedup vs baseline: 1.2115x; 1.0659x over previous
//
#include <hip/hip_runtime.h>

typedef unsigned short u16;
typedef __attribute__((ext_vector_type(8))) short bf16x8;
typedef __attribute__((ext_vector_type(4))) float f32x4;
typedef __attribute__((ext_vector_type(8))) unsigned short u16x8;

#define B_ 2
#define T_ 2048
#define C_ 2048
#define H_ 16
#define D_ 128
#define QKVW 6144  // 3*C

__device__ __forceinline__ u16 f2b(float f) {
  unsigned int x = __builtin_bit_cast(unsigned int, f);
  x += 0x7fffu + ((x >> 16) & 1u);   // round-to-nearest-even
  return (u16)(x >> 16);
}
__device__ __forceinline__ float b2f(u16 u) {
  unsigned int x = ((unsigned int)u) << 16;
  return __builtin_bit_cast(float, x);
}
__device__ __forceinline__ void gl_lds16(const void* g, void* l) {
  __builtin_amdgcn_global_load_lds((const __attribute__((address_space(1))) void*)g,
                                   (__attribute__((address_space(3))) void*)l, 16, 0, 0);
}

// ---------------- cast fp32 -> bf16 (8 elems/thread) ----------------
__global__ void castbf(const float* __restrict__ in, u16* __restrict__ out) {
  int i = blockIdx.x * 256 + threadIdx.x;
  f32x4 a = ((const f32x4*)in)[2 * i];
  f32x4 b = ((const f32x4*)in)[2 * i + 1];
  u16x8 o;
  o[0] = f2b(a[0]); o[1] = f2b(a[1]); o[2] = f2b(a[2]); o[3] = f2b(a[3]);
  o[4] = f2b(b[0]); o[5] = f2b(b[1]); o[6] = f2b(b[2]); o[7] = f2b(b[3]);
  ((u16x8*)out)[i] = o;
}

// ------------- cast + transpose: in [K][N] fp32 -> out [N][K] bf16 -------------
__global__ __launch_bounds__(256) void castT(const float* __restrict__ in,
                                             u16* __restrict__ out, int K, int N) {
  __shared__ __align__(16) u16 ld[64][72];
  const int nt = blockIdx.x * 64, kt = blockIdx.y * 64;
  const int tid = threadIdx.x;
#pragma unroll
  for (int s = 0; s < 4; ++s) {
    int idx = tid + s * 256;        // 0..1023
    int r = idx >> 4;               // k row 0..63
    int c = (idx & 15) * 4;         // n col
    f32x4 v = *(const f32x4*)(in + (size_t)(kt + r) * N + nt + c);
    ld[r][c] = f2b(v[0]); ld[r][c + 1] = f2b(v[1]);
    ld[r][c + 2] = f2b(v[2]); ld[r][c + 3] = f2b(v[3]);
  }
  __syncthreads();
#pragma unroll
  for (int s = 0; s < 2; ++s) {
    int idx = tid + s * 256;        // 0..511
    int n = idx >> 3;               // 0..63
    int c8 = (idx & 7) * 8;         // k offset
    u16x8 o;
#pragma unroll
    for (int j = 0; j < 8; ++j) o[j] = ld[c8 + j][n];
    *(u16x8*)(out + (size_t)(nt + n) * K + kt + c8) = o;
  }
}

// ---------------- 256x256 8-phase GEMM (m201-style), bf16 MFMA ----------------
// R6: grid-quantization fix. R5 analysis: 1 block/CU (128KB LDS, 244 regs),
// in-round util 43% but grid 384 = 1.5 rounds -> 33% net. Now this kernel
// only runs EXACT-round grids (NTILE param selects a tile-column subset);
// the remainder goes to gemmH (half-height tiles) so every round is full.
// Full 3-bit G4 swizzle (chunk ^= row&7); linear LDS dest (global_load_lds)
// + pre-swizzled SOURCE + swizzled read (rule #21).
__device__ __forceinline__ void stage_chunk(const u16* __restrict__ g, int K,
                                            u16* l, int ch) {
  int row = ch >> 3;
  int c = (ch & 7) ^ (row & 7);                 // inverse swizzle on source
  gl_lds16(g + (size_t)row * K + c * 8, l + ch * 8);
}

#define MFMA_Q(AF, BF, MH, NH)                                               \
  _Pragma("unroll")                                                          \
  for (int mi = 0; mi < 4; ++mi) {                                           \
    _Pragma("unroll")                                                        \
    for (int ni = 0; ni < 2; ++ni) {                                         \
      _Pragma("unroll")                                                      \
      for (int ks = 0; ks < 2; ++ks)                                         \
        acc[(MH)*4 + mi][(NH)*2 + ni] =                                      \
            __builtin_amdgcn_mfma_f32_16x16x32_bf16(                         \
                AF[mi][ks], BF[ni][ks], acc[(MH)*4 + mi][(NH)*2 + ni],       \
                0, 0, 0);                                                    \
    }                                                                        \
  }

template <int OUT_BF16>
__global__ __launch_bounds__(512, 2) void gemm256(const u16* __restrict__ A,
                                                  const u16* __restrict__ Bt,
                                                  void* __restrict__ Cout,
                                                  int M, int N, int K, int NTILE) {
  __shared__ __align__(16) u16 sm[65536];   // 128 KiB: 2 bufs x (A 32KB | B 32KB)
  const int tid = threadIdx.x;
  const int lane = tid & 63, w = tid >> 6;
  const int quad = lane >> 4, l15 = lane & 15;
  const int wm = w >> 2, wn = w & 3;        // 2 x 4 wave grid, per-wave C 128x64
  int id = blockIdx.x;
  const int cpx = gridDim.x >> 3;           // grid % 8 == 0
  id = (id & 7) * cpx + (id >> 3);          // XCD-contiguous chunks
  const int tn0 = (id % NTILE) * 256, tm0 = (id / NTILE) * 256;
  const int NT = K >> 6;
  const u16* Ag = A + (size_t)tm0 * K;
  const u16* Bg = Bt + (size_t)tn0 * K;

  f32x4 acc[8][4] = {};
  bf16x8 a0[4][2], a1[4][2], b0[2][2], b1[2][2];

  auto stA = [&](int tt, int half) {        // half 0 -> U1, 1 -> U3
    u16* l = &sm[(tt & 1) * 32768];
    const u16* g = Ag + tt * 64;
    stage_chunk(g, K, l, half * 512 + tid);
    stage_chunk(g, K, l, 1024 + half * 512 + tid);
  };
  auto stB = [&](int tt, int nh) {          // nh 0 -> U2, 1 -> U4
    u16* l = &sm[(tt & 1) * 32768 + 16384];
    const u16* g = Bg + tt * 64;
    int ch = nh * 256 + (tid & 255) + ((tid >> 8) << 9);
    stage_chunk(g, K, l, ch);
    stage_chunk(g, K, l, ch + 1024);
  };

  // prologue: T0.U1-U4, T1.U1-U3 (7 units in flight), retire T0, keep 3
  stA(0, 0); stB(0, 0); stA(0, 1); stB(0, 1);
  if (NT > 1) {
    stA(1, 0); stB(1, 0); stA(1, 1);
    asm volatile("s_waitcnt vmcnt(6)" ::: "memory");
  } else {
    asm volatile("s_waitcnt vmcnt(0)" ::: "memory");
  }
  __builtin_amdgcn_s_barrier();

  for (int t = 0; t < NT; ++t) {
    const u16* LA = &sm[(t & 1) * 32768];
    const u16* LB = LA + 16384;
    // ---- P1: read a0 (8) + b0 (4); stage (t+1).U4; MFMA Q1 ----
#pragma unroll
    for (int mi = 0; mi < 4; ++mi)
#pragma unroll
      for (int ks = 0; ks < 2; ++ks) {
        int r = wm * 128 + mi * 16 + l15;
        a0[mi][ks] = *(const bf16x8*)&LA[r * 64 +
                     ((ks * 32 + quad * 8) ^ ((r & 7) << 3))];
      }
#pragma unroll
    for (int ni = 0; ni < 2; ++ni)
#pragma unroll
      for (int ks = 0; ks < 2; ++ks) {
        int r = wn * 64 + ni * 16 + l15;
        b0[ni][ks] = *(const bf16x8*)&LB[r * 64 +
                     ((ks * 32 + quad * 8) ^ ((r & 7) << 3))];
      }
    if (t + 1 < NT) stB(t + 1, 1);
    __builtin_amdgcn_s_barrier();
    asm volatile("s_waitcnt lgkmcnt(0)");
    __builtin_amdgcn_sched_barrier(0);
    __builtin_amdgcn_s_setprio(1);
    MFMA_Q(a0, b0, 0, 0);
    __builtin_amdgcn_s_setprio(0);
    __builtin_amdgcn_s_barrier();
    // ---- P2: read b1 (4); stage (t+2).U1; MFMA Q2 ----
#pragma unroll
    for (int ni = 0; ni < 2; ++ni)
#pragma unroll
      for (int ks = 0; ks < 2; ++ks) {
        int r = wn * 64 + (ni + 2) * 16 + l15;
        b1[ni][ks] = *(const bf16x8*)&LB[r * 64 +
                     ((ks * 32 + quad * 8) ^ ((r & 7) << 3))];
      }
    if (t + 2 < NT) stA(t + 2, 0);
    __builtin_amdgcn_s_barrier();
    asm volatile("s_waitcnt lgkmcnt(0)");
    __builtin_amdgcn_sched_barrier(0);
    __builtin_amdgcn_s_setprio(1);
    MFMA_Q(a0, b1, 0, 1);
    __builtin_amdgcn_s_setprio(0);
    __builtin_amdgcn_s_barrier();
    // ---- P3: read a1 (8); stage (t+2).U2; MFMA Q3 ----
#pragma unroll
    for (int mi = 0; mi < 4; ++mi)
#pragma unroll
      for (int ks = 0; ks < 2; ++ks) {
        int r = wm * 128 + (mi + 4) * 16 + l15;
        a1[mi][ks] = *(const bf16x8*)&LA[r * 64 +
                     ((ks * 32 + quad * 8) ^ ((r & 7) << 3))];
      }
    if (t + 2 < NT) stB(t + 2, 0);
    __builtin_amdgcn_s_barrier();
    asm volatile("s_waitcnt lgkmcnt(0)");
    __builtin_amdgcn_sched_barrier(0);
    __builtin_amdgcn_s_setprio(1);
    MFMA_Q(a1, b1, 1, 1);
    __builtin_amdgcn_s_setprio(0);
    __builtin_amdgcn_s_barrier();
    // ---- P4: stage (t+2).U3; counted vmcnt; MFMA Q4 ----
    if (t + 2 < NT) {
      stA(t + 2, 1);
      asm volatile("s_waitcnt vmcnt(6)" ::: "memory");
    } else {
      asm volatile("s_waitcnt vmcnt(0)" ::: "memory");
    }
    __builtin_amdgcn_s_barrier();
    __builtin_amdgcn_s_setprio(1);
    MFMA_Q(a1, b0, 1, 0);
    __builtin_amdgcn_s_setprio(0);
    __builtin_amdgcn_s_barrier();
  }

  // epilogue: C/D layout col=lane&15, row=quad*4+reg
#pragma unroll
  for (int mi = 0; mi < 8; ++mi)
#pragma unroll
    for (int ni = 0; ni < 4; ++ni)
#pragma unroll
      for (int r = 0; r < 4; ++r) {
        int row = tm0 + wm * 128 + mi * 16 + quad * 4 + r;
        int col = tn0 + wn * 64 + ni * 16 + l15;
        float v = acc[mi][ni][r];
        if (OUT_BF16) ((u16*)Cout)[(size_t)row * N + col] = f2b(v);
        else          ((float*)Cout)[(size_t)row * N + col] = v;
      }
}

// ---------------- 128x256 BK=64 GEMM, triple-buffered (gemmH) ----------------
// R6: half-height tile for exact-round grids (gemm1 tail + all of gemm2).
// 8 waves (2x4) of 64x64; 2 phases/K-tile x 16 MFMA (R4 lesson: >=16/phase).
// LDS 3 x 48KB = 144KB: tile t+2's WHOLE 6-load stage issues at P1(t) and is
// waited (vmcnt 6) at P2(t+1) — ~3-phase lead covers HBM latency. (A 2-buf
// variant forces a 1-phase lead on the late B-half -> ~650cy stall/K-tile.)
// Ledger: reads of tile t: P1 a+b01, P2 b23 (buf t%3). buf[(t+2)%3] last
// read at P2(t-1), >=1 barrier before P1(t) ✓. vmcnt at P2(t): outstanding =
// stage(t+1)[6] + stage(t+2)[6 if issued] -> (t+2<NT) ? 6 : 0.
// B rows interleave by 32 (row = (ru>>5)*64 + h*32 + (ru&31)) so each
// half-unit's gl_lds dests are wave-contiguous; read side inverts exactly.
template <int OUT_BF16>
__global__ __launch_bounds__(512, 2) void gemmH(const u16* __restrict__ A,
                                                const u16* __restrict__ Bt,
                                                void* __restrict__ Cout,
                                                int M, int N, int K,
                                                int NTILE, int tnbase) {
  __shared__ __align__(16) u16 sm[3][24576];   // 144 KiB
  const int tid = threadIdx.x;
  const int lane = tid & 63, w = tid >> 6;
  const int quad = lane >> 4, l15 = lane & 15;
  const int wm = w >> 2, wn = w & 3;           // per-wave 64x64
  int id = blockIdx.x;
  const int cpx = gridDim.x >> 3;              // grid % 8 == 0 (256)
  id = (id & 7) * cpx + (id >> 3);
  const int tn0 = tnbase + (id % NTILE) * 256, tm0 = (id / NTILE) * 128;
  const int NT = K >> 6;
  const u16* Ag = A + (size_t)tm0 * K;
  const u16* Bg = Bt + (size_t)tn0 * K;

  f32x4 acc[4][4] = {};
  bf16x8 af[4][2], b0[2][2], b1[2][2];

  auto stage6 = [&](int tt) {                  // A(2) + Bh0(2) + Bh1(2) loads
    u16* l = sm[tt % 3];
    const u16* g = Ag + tt * 64;
    stage_chunk(g, K, l, tid);                 // A rows 0..63
    stage_chunk(g, K, l, 512 + tid);           // A rows 64..127
    const u16* gb = Bg + tt * 64;
#pragma unroll
    for (int h = 0; h < 2; ++h)
#pragma unroll
      for (int s = 0; s < 2; ++s) {
        int ch = s * 512 + tid;                // 0..1023
        int ru = ch >> 3, cc = ch & 7;
        int row = ((ru >> 5) << 6) + h * 32 + (ru & 31);
        int csrc = cc ^ (ru & 7);
        gl_lds16(gb + (size_t)row * K + csrc * 8, &l[8192 + h * 8192 + ch * 8]);
      }
  };

  // prologue: stage(0), stage(1); retire stage(0), keep stage(1) in flight
  stage6(0);
  if (NT > 1) {
    stage6(1);
    asm volatile("s_waitcnt vmcnt(6)" ::: "memory");
  } else {
    asm volatile("s_waitcnt vmcnt(0)" ::: "memory");
  }
  __builtin_amdgcn_s_barrier();

  for (int t = 0; t < NT; ++t) {
    const u16* L = sm[t % 3];
    // ---- P1: read af (8) + b0 (4); stage(t+2) 6 loads; MFMA Q1 ----
#pragma unroll
    for (int mi = 0; mi < 4; ++mi)
#pragma unroll
      for (int ks = 0; ks < 2; ++ks) {
        int r = wm * 64 + mi * 16 + l15;
        af[mi][ks] = *(const bf16x8*)&L[r * 64 +
                     ((ks * 32 + quad * 8) ^ ((r & 7) << 3))];
      }
#pragma unroll
    for (int nj = 0; nj < 2; ++nj)
#pragma unroll
      for (int ks = 0; ks < 2; ++ks) {
        int ru = wn * 32 + nj * 16 + l15;      // h=0 rows (nj 0,1)
        b0[nj][ks] = *(const bf16x8*)&L[8192 + ru * 64 +
                     ((ks * 32 + quad * 8) ^ ((ru & 7) << 3))];
      }
    if (t + 2 < NT) stage6(t + 2);
    __builtin_amdgcn_s_barrier();
    asm volatile("s_waitcnt lgkmcnt(0)");
    __builtin_amdgcn_sched_barrier(0);
    __builtin_amdgcn_s_setprio(1);
#pragma unroll
    for (int mi = 0; mi < 4; ++mi)
#pragma unroll
      for (int nj = 0; nj < 2; ++nj)
#pragma unroll
        for (int ks = 0; ks < 2; ++ks)
          acc[mi][nj] = __builtin_amdgcn_mfma_f32_16x16x32_bf16(af[mi][ks], b0[nj][ks], acc[mi][nj], 0, 0, 0);
    __builtin_amdgcn_s_setprio(0);
    __builtin_amdgcn_s_barrier();
    // ---- P2: read b1 (4); counted vmcnt; MFMA Q2 ----
#pragma unroll
    for (int nj = 0; nj < 2; ++nj)
#pragma unroll
      for (int ks = 0; ks < 2; ++ks) {
        int ru = wn * 32 + nj * 16 + l15;      // h=1 rows (nj 2,3)
        b1[nj][ks] = *(const bf16x8*)&L[16384 + ru * 64 +
                     ((ks * 32 + quad * 8) ^ ((ru & 7) << 3))];
      }
    if (t + 2 < NT)
      asm volatile("s_waitcnt vmcnt(6)" ::: "memory");   // retire stage(t+1)
    else
      asm volatile("s_waitcnt vmcnt(0)" ::: "memory");
    __builtin_amdgcn_s_barrier();
    asm volatile("s_waitcnt lgkmcnt(0)");
    __builtin_amdgcn_sched_barrier(0);
    __builtin_amdgcn_s_setprio(1);
#pragma unroll
    for (int mi = 0; mi < 4; ++mi)
#pragma unroll
      for (int nj = 0; nj < 2; ++nj)
#pragma unroll
        for (int ks = 0; ks < 2; ++ks)
          acc[mi][nj + 2] = __builtin_amdgcn_mfma_f32_16x16x32_bf16(af[mi][ks], b1[nj][ks], acc[mi][nj + 2], 0, 0, 0);
    __builtin_amdgcn_s_setprio(0);
    __builtin_amdgcn_s_barrier();
  }

  // epilogue: C/D layout col=lane&15, row=quad*4+reg
#pragma unroll
  for (int mi = 0; mi < 4; ++mi)
#pragma unroll
    for (int nj = 0; nj < 4; ++nj)
#pragma unroll
      for (int r = 0; r < 4; ++r) {
        int row = tm0 + wm * 64 + mi * 16 + quad * 4 + r;
        int col = tn0 + wn * 64 + nj * 16 + l15;
        float v = acc[mi][nj][r];
        if (OUT_BF16) ((u16*)Cout)[(size_t)row * N + col] = f2b(v);
        else          ((float*)Cout)[(size_t)row * N + col] = v;
      }
}

// ---------------- RoPE in-place on q,k of qkv (bf16), vectorized x8 ----------------
__global__ void rope_k(u16* __restrict__ qkv) {
  int g = blockIdx.x * 256 + threadIdx.x;     // 0 .. 2^20-1
  int i0 = (g & 7) * 8;                       // 8 consecutive i's
  int h = (g >> 3) & 15;
  int which = (g >> 7) & 1;
  int t = (g >> 8) & 2047;
  int b = g >> 19;
  size_t base = (size_t)(b * T_ + t) * QKVW + which * 2048 + h * 128 + i0;
  u16x8 v1 = *(const u16x8*)(qkv + base);
  u16x8 v2 = *(const u16x8*)(qkv + base + 64);
  u16x8 o1, o2;
#pragma unroll
  for (int j = 0; j < 8; ++j) {
    int i = i0 + j;
    float t1 = b2f(v1[j]), t2 = b2f(v2[j]);
    // div_i = 10000^(-i/64) ; log2(10000)/64 = 0.20762050593046439
    float ang = (float)t * exp2f(-(float)i * 0.20762050593046439f);
    float sn, cs;
    sincosf(ang, &sn, &cs);
    o1[j] = f2b(t1 * cs - t2 * sn);
    o2[j] = f2b(t2 * cs + t1 * sn);
  }
  *(u16x8*)(qkv + base) = o1;
  *(u16x8*)(qkv + base + 64) = o2;
}

// ---------------- transpose V -> Vt [B*H][D][T] (bf16) ----------------
__global__ __launch_bounds__(256) void vtrans(const u16* __restrict__ qkv, u16* __restrict__ vt) {
  __shared__ __align__(16) u16 ld[128][136];
  const int tt = blockIdx.x, bh = blockIdx.y;
  const int b = bh >> 4, h = bh & 15;
  const u16* vb = qkv + (size_t)b * T_ * QKVW + 4096 + h * 128;
  const int tid = threadIdx.x;
#pragma unroll
  for (int s = 0; s < 8; ++s) {
    int t = (tid >> 4) + s * 16;
    int d0 = (tid & 15) * 8;
    *(bf16x8*)&ld[t][d0] = *(const bf16x8*)(vb + (size_t)(tt * 128 + t) * QKVW + d0);
  }
  __syncthreads();
  u16* vout = vt + (size_t)bh * D_ * T_ + tt * 128;
#pragma unroll
  for (int s = 0; s < 8; ++s) {
    int d = (tid >> 4) + s * 16;
    int t0 = (tid & 15) * 8;
    u16x8 o;
#pragma unroll
    for (int j = 0; j < 8; ++j) o[j] = ld[t0 + j][d];
    *(u16x8*)(vout + (size_t)d * T_ + t0) = o;
  }
}

// ---------------- flash attention (causal, online softmax) ----------------
// R5 structure kept: causal pairing (jA=jp, jB=31-jp), shared K-fragments
// across the pair, gl_lds + 3-bit XOR swizzle, K/V dbuf, per-lane partial
// l-sum, ballot-gated defer-max, T5 setprio.
// NOTE reference gotcha: out = einsum('bhts,bshd->bhtd').reshape(B,T,C) is a
// FLAT reshape of (B,H,T,D): element (b,h,t,d) sits at ((b*H+h)*T+t)*D+d.
#define APW 72    // P tile row stride (u16)
__global__ __launch_bounds__(256, 2) void attn(const u16* __restrict__ qkv,
                                               const u16* __restrict__ vt,
                                               u16* __restrict__ obuf) {
  __shared__ __align__(16) u16 lK[2][64 * 128];    // 2 x 16 KB, swizzled
  __shared__ __align__(16) u16 lV[2][128 * 64];    // 2 x 16 KB, swizzled
  __shared__ __align__(16) u16 lP[64 * APW];       // 9 KB, wave-private rows
  const int tid = threadIdx.x, lane = tid & 63, w = tid >> 6;
  const int quad = lane >> 4, l15 = lane & 15;
  const int bh = blockIdx.x, jp = blockIdx.y;
  const int jA = jp, jB = 31 - jp;                 // jA in 0..15, jB in 16..31
  const int b = bh >> 4, h = bh & 15;
  const u16* qb = qkv + (size_t)b * T_ * QKVW + h * 128;
  const u16* kb = qb + 2048;
  const u16* vtb = vt + (size_t)bh * D_ * T_;

  bf16x8 qfA[4], qfB[4];
#pragma unroll
  for (int kk = 0; kk < 4; ++kk) {
    qfA[kk] = *(const bf16x8*)(qb + (size_t)(jA * 64 + w * 16 + l15) * QKVW + kk * 32 + quad * 8);
    qfB[kk] = *(const bf16x8*)(qb + (size_t)(jB * 64 + w * 16 + l15) * QKVW + kk * 32 + quad * 8);
  }

  f32x4 oA[8] = {}, oB[8] = {};
  float mA[4], lAr[4], mB[4], lBr[4];
#pragma unroll
  for (int r = 0; r < 4; ++r) {
    mA[r] = -__builtin_inff(); lAr[r] = 0.f;
    mB[r] = -__builtin_inff(); lBr[r] = 0.f;
  }
  const float sc = 0.08838834764831845f * 1.4426950408889634f;  // 1/sqrt(128) * log2(e)

  auto stage = [&](int kt, int buf) {
#pragma unroll
    for (int s = 0; s < 4; ++s) {
      int ch = tid + s * 256;                        // 0..1023
      int kr = ch >> 4, kc = (ch & 15) ^ (kr & 7);   // K row 0..63, 16 chunks/row
      gl_lds16(kb + (size_t)(kt * 64 + kr) * QKVW + kc * 8, &lK[buf][ch * 8]);
      int vr = ch >> 3, vc = (ch & 7) ^ (vr & 7);    // V row 0..127, 8 chunks/row
      gl_lds16(vtb + (size_t)vr * T_ + kt * 64 + vc * 8, &lV[buf][ch * 8]);
    }
  };

  // softmax + PV for one q-tile's S-accumulator (QK^T already done)
  auto smpv = [&](f32x4* sacc, f32x4* oacc, float* mrow, float* lrow,
                  int jw, int kt, int cb) {
    const bool diag = (kt == jw);
#pragma unroll
    for (int nj = 0; nj < 4; ++nj) {
      int key = nj * 16 + l15;                 // local key 0..63
#pragma unroll
      for (int r = 0; r < 4; ++r) {
        float s = sacc[nj][r] * sc;
        if (diag) {
          int qrow = w * 16 + quad * 4 + r;    // local q 0..63
          if (key > qrow) s = -__builtin_inff();
        }
        sacc[nj][r] = s;
      }
    }
    // per-lane partial max + single ballot defer-check (T13)
    float pm[4];
#pragma unroll
    for (int r = 0; r < 4; ++r)
      pm[r] = fmaxf(fmaxf(sacc[0][r], sacc[1][r]), fmaxf(sacc[2][r], sacc[3][r]));
    float dmax = fmaxf(fmaxf(pm[0] - mrow[0], pm[1] - mrow[1]),
                       fmaxf(pm[2] - mrow[2], pm[3] - mrow[3]));
    if (__any(dmax > 11.5f)) {                 // rare: real max growth
#pragma unroll
      for (int r = 0; r < 4; ++r) {
        float rm = pm[r];
        rm = fmaxf(rm, __shfl_xor(rm, 1));
        rm = fmaxf(rm, __shfl_xor(rm, 2));
        rm = fmaxf(rm, __shfl_xor(rm, 4));
        rm = fmaxf(rm, __shfl_xor(rm, 8));
        float mold = mrow[r];
        float mnew = fmaxf(mold, rm);
        float alpha = exp2f(mold - mnew);
#pragma unroll
        for (int nd = 0; nd < 8; ++nd) oacc[nd][r] *= alpha;
        lrow[r] *= alpha;
        mrow[r] = mnew;
      }
    }
#pragma unroll
    for (int r = 0; r < 4; ++r) {
      int prow = w * 16 + quad * 4 + r;        // wave-private P row
      float rs = 0.f;
#pragma unroll
      for (int nj = 0; nj < 4; ++nj) {
        float p = exp2f(sacc[nj][r] - mrow[r]);
        rs += p;
        lP[prow * APW + nj * 16 + l15] = f2b(p);
      }
      lrow[r] += rs;                           // per-lane partial (no shfl)
    }
    // PV: O += P * V  (P rows wave-private — no barrier needed)
#pragma unroll
    for (int kk = 0; kk < 2; ++kk) {
      bf16x8 pf, vf[8];
      pf = *(const bf16x8*)&lP[(w * 16 + l15) * APW + kk * 32 + quad * 8];
#pragma unroll
      for (int nd = 0; nd < 8; ++nd) {
        int r = nd * 16 + l15;
        vf[nd] = *(const bf16x8*)&lV[cb][r * 64 + ((kk * 32 + quad * 8) ^ ((r & 7) << 3))];
      }
      __builtin_amdgcn_s_setprio(1);
#pragma unroll
      for (int nd = 0; nd < 8; ++nd)
        oacc[nd] = __builtin_amdgcn_mfma_f32_16x16x32_bf16(pf, vf[nd], oacc[nd], 0, 0, 0);
      __builtin_amdgcn_s_setprio(0);
    }
  };

  stage(0, 0);
  __syncthreads();   // drains vmcnt (implicit in __syncthreads)

  for (int kt = 0; kt <= jB; ++kt) {
    int cb = kt & 1;
    if (kt < jB) stage(kt + 1, cb ^ 1);       // overlap next-tile DMA with compute
    const bool doA = (kt <= jA);
    // QK^T for B (and A when paired) with a SINGLE kf load per kk
    f32x4 sB[4] = {}, sA[4] = {};
#pragma unroll
    for (int kk = 0; kk < 4; ++kk) {
      bf16x8 kf[4];
#pragma unroll
      for (int nj = 0; nj < 4; ++nj) {
        int r = nj * 16 + l15;
        kf[nj] = *(const bf16x8*)&lK[cb][r * 128 + ((kk * 32 + quad * 8) ^ ((r & 7) << 3))];
      }
      __builtin_amdgcn_s_setprio(1);
#pragma unroll
      for (int nj = 0; nj < 4; ++nj)
        sB[nj] = __builtin_amdgcn_mfma_f32_16x16x32_bf16(qfB[kk], kf[nj], sB[nj], 0, 0, 0);
      if (doA)
#pragma unroll
        for (int nj = 0; nj < 4; ++nj)
          sA[nj] = __builtin_amdgcn_mfma_f32_16x16x32_bf16(qfA[kk], kf[nj], sA[nj], 0, 0, 0);
      __builtin_amdgcn_s_setprio(0);
    }
    smpv(sB, oB, mB, lBr, jB, kt, cb);
    if (doA) smpv(sA, oA, mA, lAr, jA, kt, cb);
    __syncthreads();                          // drains stage DMA + LDS, swap bufs
  }

  // single cross-lane reduction of the per-lane l partials
#pragma unroll
  for (int r = 0; r < 4; ++r) {
    float sA = lAr[r], sB = lBr[r];
    sA += __shfl_xor(sA, 1); sB += __shfl_xor(sB, 1);
    sA += __shfl_xor(sA, 2); sB += __shfl_xor(sB, 2);
    sA += __shfl_xor(sA, 4); sB += __shfl_xor(sB, 4);
    sA += __shfl_xor(sA, 8); sB += __shfl_xor(sB, 8);
    lAr[r] = sA; lBr[r] = sB;
  }

  // epilogue: O / l -> bf16, REFERENCE-MATCHED layout [B*H][T][D] (see note)
#pragma unroll
  for (int nd = 0; nd < 8; ++nd)
#pragma unroll
    for (int r = 0; r < 4; ++r) {
      int dcol = nd * 16 + l15;
      int qrB = jB * 64 + w * 16 + quad * 4 + r;
      obuf[((size_t)bh * T_ + qrB) * D_ + dcol] = f2b(oB[nd][r] / lBr[r]);
      int qrA = jA * 64 + w * 16 + quad * 4 + r;
      obuf[((size_t)bh * T_ + qrA) * D_ + dcol] = f2b(oA[nd][r] / lAr[r]);
    }
}

extern "C" void kernel_launch(void* const* d_in, const int* in_sizes, int n_in,
                              void* d_out, int out_size, void* d_ws, size_t ws_size,
                              hipStream_t stream) {
  const float* x = (const float*)d_in[0];
  const float* Wqkv = (const float*)d_in[1];
  const float* Wout = (const float*)d_in[2];
  float* out = (float*)d_out;
  char* ws = (char*)d_ws;

  // workspace layout (bytes):
  //   [0,            16777216)  xb (x bf16)   -- later reused as Ob (attn out bf16)
  //   [16777216,     41943040)  Wqkv_t bf16   -- later reused as Wout_t bf16
  //   [41943040,     92274688)  qkv bf16 [4096][6144]
  //   [92274688,    109051904)  Vt bf16 [B*H][128][2048]
  u16* xb   = (u16*)ws;
  u16* wqt  = (u16*)(ws + 16777216);
  u16* qkvb = (u16*)(ws + 41943040);
  u16* vtb  = (u16*)(ws + 92274688);
  u16* wot  = wqt;   // alias: cast after GEMM1 consumed Wqkv_t
  u16* ob   = xb;    // alias: attn output after GEMM1 consumed xb

  castbf<<<4096, 256, 0, stream>>>(x, xb);                                  // 8.4M elems
  castT<<<dim3(96, 32), 256, 0, stream>>>(Wqkv, wqt, 2048, 6144);
  // gemm1 split into two exact rounds: 256 full tiles (n 0..15) + 256 half
  // tiles (n 16..23) -> makespan T + T/2 instead of 2T (384 @ 1 block/CU).
  gemm256<1><<<dim3(256), 512, 0, stream>>>(xb, wqt, qkvb, 4096, 6144, 2048, 16);
  gemmH<1><<<dim3(256), 512, 0, stream>>>(xb, wqt, qkvb, 4096, 6144, 2048, 8, 4096);
  castT<<<dim3(32, 32), 256, 0, stream>>>(Wout, wot, 2048, 2048);
  rope_k<<<4096, 256, 0, stream>>>(qkvb);
  vtrans<<<dim3(16, 32), 256, 0, stream>>>(qkvb, vtb);
  attn<<<dim3(32, 16), 256, 0, stream>>>(qkvb, vtb, ob);   // (bh, jpair)
  // gemm2 as 256 half-tiles: one exact round of half-duration blocks.
  gemmH<0><<<dim3(256), 512, 0, stream>>>(ob, wot, out, 4096, 2048, 2048, 8, 0);
}

// Round 9
// 369.712 us; speedup vs baseline: 1.2320x; 1.0169x over previous
//
#include <hip/hip_runtime.h>

typedef unsigned short u16;
typedef __attribute__((ext_vector_type(8))) short bf16x8;
typedef __attribute__((ext_vector_type(4))) float f32x4;
typedef __attribute__((ext_vector_type(8))) unsigned short u16x8;

#define B_ 2
#define T_ 2048
#define C_ 2048
#define H_ 16
#define D_ 128
#define QKVW 6144  // 3*C

__device__ __forceinline__ u16 f2b(float f) {
  unsigned int x = __builtin_bit_cast(unsigned int, f);
  x += 0x7fffu + ((x >> 16) & 1u);   // round-to-nearest-even
  return (u16)(x >> 16);
}
__device__ __forceinline__ float b2f(u16 u) {
  unsigned int x = ((unsigned int)u) << 16;
  return __builtin_bit_cast(float, x);
}
__device__ __forceinline__ void gl_lds16(const void* g, void* l) {
  __builtin_amdgcn_global_load_lds((const __attribute__((address_space(1))) void*)g,
                                   (__attribute__((address_space(3))) void*)l, 16, 0, 0);
}

// ---------------- cast fp32 -> bf16 (8 elems/thread) ----------------
__global__ void castbf(const float* __restrict__ in, u16* __restrict__ out) {
  int i = blockIdx.x * 256 + threadIdx.x;
  f32x4 a = ((const f32x4*)in)[2 * i];
  f32x4 b = ((const f32x4*)in)[2 * i + 1];
  u16x8 o;
  o[0] = f2b(a[0]); o[1] = f2b(a[1]); o[2] = f2b(a[2]); o[3] = f2b(a[3]);
  o[4] = f2b(b[0]); o[5] = f2b(b[1]); o[6] = f2b(b[2]); o[7] = f2b(b[3]);
  ((u16x8*)out)[i] = o;
}

// ------------- cast + transpose: in [K][N] fp32 -> out [N][K] bf16 -------------
__global__ __launch_bounds__(256) void castT(const float* __restrict__ in,
                                             u16* __restrict__ out, int K, int N) {
  __shared__ __align__(16) u16 ld[64][72];
  const int nt = blockIdx.x * 64, kt = blockIdx.y * 64;
  const int tid = threadIdx.x;
#pragma unroll
  for (int s = 0; s < 4; ++s) {
    int idx = tid + s * 256;        // 0..1023
    int r = idx >> 4;               // k row 0..63
    int c = (idx & 15) * 4;         // n col
    f32x4 v = *(const f32x4*)(in + (size_t)(kt + r) * N + nt + c);
    ld[r][c] = f2b(v[0]); ld[r][c + 1] = f2b(v[1]);
    ld[r][c + 2] = f2b(v[2]); ld[r][c + 3] = f2b(v[3]);
  }
  __syncthreads();
#pragma unroll
  for (int s = 0; s < 2; ++s) {
    int idx = tid + s * 256;        // 0..511
    int n = idx >> 3;               // 0..63
    int c8 = (idx & 7) * 8;         // k offset
    u16x8 o;
#pragma unroll
    for (int j = 0; j < 8; ++j) o[j] = ld[c8 + j][n];
    *(u16x8*)(out + (size_t)(nt + n) * K + kt + c8) = o;
  }
}

// ---------------- 256x256 8-phase GEMM (m201-style), bf16 MFMA ----------------
// Exact-round grids only (NTILE selects tile-column subset); remainder goes
// to gemmH. Full 3-bit G4 swizzle (chunk ^= row&7); linear LDS dest
// (global_load_lds) + pre-swizzled SOURCE + swizzled read (rule #21).
__device__ __forceinline__ void stage_chunk(const u16* __restrict__ g, int K,
                                            u16* l, int ch) {
  int row = ch >> 3;
  int c = (ch & 7) ^ (row & 7);                 // inverse swizzle on source
  gl_lds16(g + (size_t)row * K + c * 8, l + ch * 8);
}

#define MFMA_Q(AF, BF, MH, NH)                                               \
  _Pragma("unroll")                                                          \
  for (int mi = 0; mi < 4; ++mi) {                                           \
    _Pragma("unroll")                                                        \
    for (int ni = 0; ni < 2; ++ni) {                                         \
      _Pragma("unroll")                                                      \
      for (int ks = 0; ks < 2; ++ks)                                         \
        acc[(MH)*4 + mi][(NH)*2 + ni] =                                      \
            __builtin_amdgcn_mfma_f32_16x16x32_bf16(                         \
                AF[mi][ks], BF[ni][ks], acc[(MH)*4 + mi][(NH)*2 + ni],       \
                0, 0, 0);                                                    \
    }                                                                        \
  }

template <int OUT_BF16>
__global__ __launch_bounds__(512, 2) void gemm256(const u16* __restrict__ A,
                                                  const u16* __restrict__ Bt,
                                                  void* __restrict__ Cout,
                                                  int M, int N, int K, int NTILE) {
  __shared__ __align__(16) u16 sm[65536];   // 128 KiB: 2 bufs x (A 32KB | B 32KB)
  const int tid = threadIdx.x;
  const int lane = tid & 63, w = tid >> 6;
  const int quad = lane >> 4, l15 = lane & 15;
  const int wm = w >> 2, wn = w & 3;        // 2 x 4 wave grid, per-wave C 128x64
  int id = blockIdx.x;
  const int cpx = gridDim.x >> 3;           // grid % 8 == 0
  id = (id & 7) * cpx + (id >> 3);          // XCD-contiguous chunks
  const int tn0 = (id % NTILE) * 256, tm0 = (id / NTILE) * 256;
  const int NT = K >> 6;
  const u16* Ag = A + (size_t)tm0 * K;
  const u16* Bg = Bt + (size_t)tn0 * K;

  f32x4 acc[8][4] = {};
  bf16x8 a0[4][2], a1[4][2], b0[2][2], b1[2][2];

  auto stA = [&](int tt, int half) {        // half 0 -> U1, 1 -> U3
    u16* l = &sm[(tt & 1) * 32768];
    const u16* g = Ag + tt * 64;
    stage_chunk(g, K, l, half * 512 + tid);
    stage_chunk(g, K, l, 1024 + half * 512 + tid);
  };
  auto stB = [&](int tt, int nh) {          // nh 0 -> U2, 1 -> U4
    u16* l = &sm[(tt & 1) * 32768 + 16384];
    const u16* g = Bg + tt * 64;
    int ch = nh * 256 + (tid & 255) + ((tid >> 8) << 9);
    stage_chunk(g, K, l, ch);
    stage_chunk(g, K, l, ch + 1024);
  };

  // prologue: T0.U1-U4, T1.U1-U3 (7 units in flight), retire T0, keep 3
  stA(0, 0); stB(0, 0); stA(0, 1); stB(0, 1);
  if (NT > 1) {
    stA(1, 0); stB(1, 0); stA(1, 1);
    asm volatile("s_waitcnt vmcnt(6)" ::: "memory");
  } else {
    asm volatile("s_waitcnt vmcnt(0)" ::: "memory");
  }
  __builtin_amdgcn_s_barrier();

  for (int t = 0; t < NT; ++t) {
    const u16* LA = &sm[(t & 1) * 32768];
    const u16* LB = LA + 16384;
    // ---- P1: read a0 (8) + b0 (4); stage (t+1).U4; MFMA Q1 ----
#pragma unroll
    for (int mi = 0; mi < 4; ++mi)
#pragma unroll
      for (int ks = 0; ks < 2; ++ks) {
        int r = wm * 128 + mi * 16 + l15;
        a0[mi][ks] = *(const bf16x8*)&LA[r * 64 +
                     ((ks * 32 + quad * 8) ^ ((r & 7) << 3))];
      }
#pragma unroll
    for (int ni = 0; ni < 2; ++ni)
#pragma unroll
      for (int ks = 0; ks < 2; ++ks) {
        int r = wn * 64 + ni * 16 + l15;
        b0[ni][ks] = *(const bf16x8*)&LB[r * 64 +
                     ((ks * 32 + quad * 8) ^ ((r & 7) << 3))];
      }
    if (t + 1 < NT) stB(t + 1, 1);
    __builtin_amdgcn_s_barrier();
    asm volatile("s_waitcnt lgkmcnt(0)");
    __builtin_amdgcn_sched_barrier(0);
    __builtin_amdgcn_s_setprio(1);
    MFMA_Q(a0, b0, 0, 0);
    __builtin_amdgcn_s_setprio(0);
    __builtin_amdgcn_s_barrier();
    // ---- P2: read b1 (4); stage (t+2).U1; MFMA Q2 ----
#pragma unroll
    for (int ni = 0; ni < 2; ++ni)
#pragma unroll
      for (int ks = 0; ks < 2; ++ks) {
        int r = wn * 64 + (ni + 2) * 16 + l15;
        b1[ni][ks] = *(const bf16x8*)&LB[r * 64 +
                     ((ks * 32 + quad * 8) ^ ((r & 7) << 3))];
      }
    if (t + 2 < NT) stA(t + 2, 0);
    __builtin_amdgcn_s_barrier();
    asm volatile("s_waitcnt lgkmcnt(0)");
    __builtin_amdgcn_sched_barrier(0);
    __builtin_amdgcn_s_setprio(1);
    MFMA_Q(a0, b1, 0, 1);
    __builtin_amdgcn_s_setprio(0);
    __builtin_amdgcn_s_barrier();
    // ---- P3: read a1 (8); stage (t+2).U2; MFMA Q3 ----
#pragma unroll
    for (int mi = 0; mi < 4; ++mi)
#pragma unroll
      for (int ks = 0; ks < 2; ++ks) {
        int r = wm * 128 + (mi + 4) * 16 + l15;
        a1[mi][ks] = *(const bf16x8*)&LA[r * 64 +
                     ((ks * 32 + quad * 8) ^ ((r & 7) << 3))];
      }
    if (t + 2 < NT) stB(t + 2, 0);
    __builtin_amdgcn_s_barrier();
    asm volatile("s_waitcnt lgkmcnt(0)");
    __builtin_amdgcn_sched_barrier(0);
    __builtin_amdgcn_s_setprio(1);
    MFMA_Q(a1, b1, 1, 1);
    __builtin_amdgcn_s_setprio(0);
    __builtin_amdgcn_s_barrier();
    // ---- P4: stage (t+2).U3; counted vmcnt; MFMA Q4 ----
    if (t + 2 < NT) {
      stA(t + 2, 1);
      asm volatile("s_waitcnt vmcnt(6)" ::: "memory");
    } else {
      asm volatile("s_waitcnt vmcnt(0)" ::: "memory");
    }
    __builtin_amdgcn_s_barrier();
    __builtin_amdgcn_s_setprio(1);
    MFMA_Q(a1, b0, 1, 0);
    __builtin_amdgcn_s_setprio(0);
    __builtin_amdgcn_s_barrier();
  }

  // epilogue: C/D layout col=lane&15, row=quad*4+reg
#pragma unroll
  for (int mi = 0; mi < 8; ++mi)
#pragma unroll
    for (int ni = 0; ni < 4; ++ni)
#pragma unroll
      for (int r = 0; r < 4; ++r) {
        int row = tm0 + wm * 128 + mi * 16 + quad * 4 + r;
        int col = tn0 + wn * 64 + ni * 16 + l15;
        float v = acc[mi][ni][r];
        if (OUT_BF16) ((u16*)Cout)[(size_t)row * N + col] = f2b(v);
        else          ((float*)Cout)[(size_t)row * N + col] = v;
      }
}

// ---------------- 128x256 BK=64 GEMM, triple-buffered (gemmH) ----------------
// Half-height tile for exact-round grids (gemm1 tail + all of gemm2).
// 8 waves (2x4) of 64x64; 2 phases/K-tile x 16 MFMA. LDS 3 x 48KB = 144KB:
// tile t+2's whole 6-load stage issues at P1(t), waited (vmcnt 6) at P2(t+1).
template <int OUT_BF16>
__global__ __launch_bounds__(512, 2) void gemmH(const u16* __restrict__ A,
                                                const u16* __restrict__ Bt,
                                                void* __restrict__ Cout,
                                                int M, int N, int K,
                                                int NTILE, int tnbase) {
  __shared__ __align__(16) u16 sm[3][24576];   // 144 KiB
  const int tid = threadIdx.x;
  const int lane = tid & 63, w = tid >> 6;
  const int quad = lane >> 4, l15 = lane & 15;
  const int wm = w >> 2, wn = w & 3;           // per-wave 64x64
  int id = blockIdx.x;
  const int cpx = gridDim.x >> 3;              // grid % 8 == 0 (256)
  id = (id & 7) * cpx + (id >> 3);
  const int tn0 = tnbase + (id % NTILE) * 256, tm0 = (id / NTILE) * 128;
  const int NT = K >> 6;
  const u16* Ag = A + (size_t)tm0 * K;
  const u16* Bg = Bt + (size_t)tn0 * K;

  f32x4 acc[4][4] = {};
  bf16x8 af[4][2], b0[2][2], b1[2][2];

  auto stage6 = [&](int tt) {                  // A(2) + Bh0(2) + Bh1(2) loads
    u16* l = sm[tt % 3];
    const u16* g = Ag + tt * 64;
    stage_chunk(g, K, l, tid);                 // A rows 0..63
    stage_chunk(g, K, l, 512 + tid);           // A rows 64..127
    const u16* gb = Bg + tt * 64;
#pragma unroll
    for (int h = 0; h < 2; ++h)
#pragma unroll
      for (int s = 0; s < 2; ++s) {
        int ch = s * 512 + tid;                // 0..1023
        int ru = ch >> 3, cc = ch & 7;
        int row = ((ru >> 5) << 6) + h * 32 + (ru & 31);
        int csrc = cc ^ (ru & 7);
        gl_lds16(gb + (size_t)row * K + csrc * 8, &l[8192 + h * 8192 + ch * 8]);
      }
  };

  // prologue: stage(0), stage(1); retire stage(0), keep stage(1) in flight
  stage6(0);
  if (NT > 1) {
    stage6(1);
    asm volatile("s_waitcnt vmcnt(6)" ::: "memory");
  } else {
    asm volatile("s_waitcnt vmcnt(0)" ::: "memory");
  }
  __builtin_amdgcn_s_barrier();

  for (int t = 0; t < NT; ++t) {
    const u16* L = sm[t % 3];
    // ---- P1: read af (8) + b0 (4); stage(t+2) 6 loads; MFMA Q1 ----
#pragma unroll
    for (int mi = 0; mi < 4; ++mi)
#pragma unroll
      for (int ks = 0; ks < 2; ++ks) {
        int r = wm * 64 + mi * 16 + l15;
        af[mi][ks] = *(const bf16x8*)&L[r * 64 +
                     ((ks * 32 + quad * 8) ^ ((r & 7) << 3))];
      }
#pragma unroll
    for (int nj = 0; nj < 2; ++nj)
#pragma unroll
      for (int ks = 0; ks < 2; ++ks) {
        int ru = wn * 32 + nj * 16 + l15;      // h=0 rows (nj 0,1)
        b0[nj][ks] = *(const bf16x8*)&L[8192 + ru * 64 +
                     ((ks * 32 + quad * 8) ^ ((ru & 7) << 3))];
      }
    if (t + 2 < NT) stage6(t + 2);
    __builtin_amdgcn_s_barrier();
    asm volatile("s_waitcnt lgkmcnt(0)");
    __builtin_amdgcn_sched_barrier(0);
    __builtin_amdgcn_s_setprio(1);
#pragma unroll
    for (int mi = 0; mi < 4; ++mi)
#pragma unroll
      for (int nj = 0; nj < 2; ++nj)
#pragma unroll
        for (int ks = 0; ks < 2; ++ks)
          acc[mi][nj] = __builtin_amdgcn_mfma_f32_16x16x32_bf16(af[mi][ks], b0[nj][ks], acc[mi][nj], 0, 0, 0);
    __builtin_amdgcn_s_setprio(0);
    __builtin_amdgcn_s_barrier();
    // ---- P2: read b1 (4); counted vmcnt; MFMA Q2 ----
#pragma unroll
    for (int nj = 0; nj < 2; ++nj)
#pragma unroll
      for (int ks = 0; ks < 2; ++ks) {
        int ru = wn * 32 + nj * 16 + l15;      // h=1 rows (nj 2,3)
        b1[nj][ks] = *(const bf16x8*)&L[16384 + ru * 64 +
                     ((ks * 32 + quad * 8) ^ ((ru & 7) << 3))];
      }
    if (t + 2 < NT)
      asm volatile("s_waitcnt vmcnt(6)" ::: "memory");   // retire stage(t+1)
    else
      asm volatile("s_waitcnt vmcnt(0)" ::: "memory");
    __builtin_amdgcn_s_barrier();
    asm volatile("s_waitcnt lgkmcnt(0)");
    __builtin_amdgcn_sched_barrier(0);
    __builtin_amdgcn_s_setprio(1);
#pragma unroll
    for (int mi = 0; mi < 4; ++mi)
#pragma unroll
      for (int nj = 0; nj < 2; ++nj)
#pragma unroll
        for (int ks = 0; ks < 2; ++ks)
          acc[mi][nj + 2] = __builtin_amdgcn_mfma_f32_16x16x32_bf16(af[mi][ks], b1[nj][ks], acc[mi][nj + 2], 0, 0, 0);
    __builtin_amdgcn_s_setprio(0);
    __builtin_amdgcn_s_barrier();
  }

  // epilogue: C/D layout col=lane&15, row=quad*4+reg
#pragma unroll
  for (int mi = 0; mi < 4; ++mi)
#pragma unroll
    for (int nj = 0; nj < 4; ++nj)
#pragma unroll
      for (int r = 0; r < 4; ++r) {
        int row = tm0 + wm * 64 + mi * 16 + quad * 4 + r;
        int col = tn0 + wn * 64 + nj * 16 + l15;
        float v = acc[mi][nj][r];
        if (OUT_BF16) ((u16*)Cout)[(size_t)row * N + col] = f2b(v);
        else          ((float*)Cout)[(size_t)row * N + col] = v;
      }
}

// ------------- RoPE in-place on q,k of qkv (bf16), vectorized x8 -------------
// R9: pre-scale q (which==0) by 1/sqrt(D)*log2e so attn's QK^T comes out
// already in exp2-ready units — removes the per-element scale mul (and for
// non-diag tiles the whole mask/scale pass) from attn's hot loop.
__global__ void rope_k(u16* __restrict__ qkv) {
  int g = blockIdx.x * 256 + threadIdx.x;     // 0 .. 2^20-1
  int i0 = (g & 7) * 8;                       // 8 consecutive i's
  int h = (g >> 3) & 15;
  int which = (g >> 7) & 1;
  int t = (g >> 8) & 2047;
  int b = g >> 19;
  size_t base = (size_t)(b * T_ + t) * QKVW + which * 2048 + h * 128 + i0;
  const float qs = which ? 1.0f : 0.08838834764831845f * 1.4426950408889634f;
  u16x8 v1 = *(const u16x8*)(qkv + base);
  u16x8 v2 = *(const u16x8*)(qkv + base + 64);
  u16x8 o1, o2;
#pragma unroll
  for (int j = 0; j < 8; ++j) {
    int i = i0 + j;
    float t1 = b2f(v1[j]), t2 = b2f(v2[j]);
    // div_i = 10000^(-i/64) ; log2(10000)/64 = 0.20762050593046439
    float ang = (float)t * exp2f(-(float)i * 0.20762050593046439f);
    float sn, cs;
    sincosf(ang, &sn, &cs);
    o1[j] = f2b((t1 * cs - t2 * sn) * qs);
    o2[j] = f2b((t2 * cs + t1 * sn) * qs);
  }
  *(u16x8*)(qkv + base) = o1;
  *(u16x8*)(qkv + base + 64) = o2;
}

// ---------------- transpose V -> Vt [B*H][D][T] (bf16) ----------------
__global__ __launch_bounds__(256) void vtrans(const u16* __restrict__ qkv, u16* __restrict__ vt) {
  __shared__ __align__(16) u16 ld[128][136];
  const int tt = blockIdx.x, bh = blockIdx.y;
  const int b = bh >> 4, h = bh & 15;
  const u16* vb = qkv + (size_t)b * T_ * QKVW + 4096 + h * 128;
  const int tid = threadIdx.x;
#pragma unroll
  for (int s = 0; s < 8; ++s) {
    int t = (tid >> 4) + s * 16;
    int d0 = (tid & 15) * 8;
    *(bf16x8*)&ld[t][d0] = *(const bf16x8*)(vb + (size_t)(tt * 128 + t) * QKVW + d0);
  }
  __syncthreads();
  u16* vout = vt + (size_t)bh * D_ * T_ + tt * 128;
#pragma unroll
  for (int s = 0; s < 8; ++s) {
    int d = (tid >> 4) + s * 16;
    int t0 = (tid & 15) * 8;
    u16x8 o;
#pragma unroll
    for (int j = 0; j < 8; ++j) o[j] = ld[t0 + j][d];
    *(u16x8*)(vout + (size_t)d * T_ + t0) = o;
  }
}

// ---------------- flash attention (causal, online softmax) ----------------
// R9: (a) APW 72->76. Bank math: old dword stride 36≡4 (mod 32) put quads
// {0,2}/{1,3} on identical banks -> 4-way conflict on every P-write (the
// stable 3.75M counter). Stride 38≡6: quad offsets {0,24,16,8} distinct,
// l15*38 spans 16 banks -> P-writes and pf reads conflict-free.
// (b) Q pre-scaled in rope_k -> mask/scale pass now DIAG-ONLY (32 of 33
// tiles skip it; 16 v_mul/smpv removed from all tiles).
// Kept: causal pairing, shared K-fragments, gl_lds + 3-bit XOR swizzle,
// K/V dbuf, per-lane partial l-sum, ballot-gated defer-max, T5 setprio.
// NOTE reference gotcha: out = einsum('bhts,bshd->bhtd').reshape(B,T,C) is a
// FLAT reshape of (B,H,T,D): element (b,h,t,d) sits at ((b*H+h)*T+t)*D+d.
#define APW 76    // P tile row stride (u16); dword stride 38 (gcd(6,32)=2)
__global__ __launch_bounds__(256, 2) void attn(const u16* __restrict__ qkv,
                                               const u16* __restrict__ vt,
                                               u16* __restrict__ obuf) {
  __shared__ __align__(16) u16 lK[2][64 * 128];    // 2 x 16 KB, swizzled
  __shared__ __align__(16) u16 lV[2][128 * 64];    // 2 x 16 KB, swizzled
  __shared__ __align__(16) u16 lP[64 * APW];       // 9.5 KB, wave-private rows
  const int tid = threadIdx.x, lane = tid & 63, w = tid >> 6;
  const int quad = lane >> 4, l15 = lane & 15;
  const int bh = blockIdx.x, jp = blockIdx.y;
  const int jA = jp, jB = 31 - jp;                 // jA in 0..15, jB in 16..31
  const int b = bh >> 4, h = bh & 15;
  const u16* qb = qkv + (size_t)b * T_ * QKVW + h * 128;
  const u16* kb = qb + 2048;
  const u16* vtb = vt + (size_t)bh * D_ * T_;

  bf16x8 qfA[4], qfB[4];
#pragma unroll
  for (int kk = 0; kk < 4; ++kk) {
    qfA[kk] = *(const bf16x8*)(qb + (size_t)(jA * 64 + w * 16 + l15) * QKVW + kk * 32 + quad * 8);
    qfB[kk] = *(const bf16x8*)(qb + (size_t)(jB * 64 + w * 16 + l15) * QKVW + kk * 32 + quad * 8);
  }

  f32x4 oA[8] = {}, oB[8] = {};
  float mA[4], lAr[4], mB[4], lBr[4];
#pragma unroll
  for (int r = 0; r < 4; ++r) {
    mA[r] = -__builtin_inff(); lAr[r] = 0.f;
    mB[r] = -__builtin_inff(); lBr[r] = 0.f;
  }

  auto stage = [&](int kt, int buf) {
#pragma unroll
    for (int s = 0; s < 4; ++s) {
      int ch = tid + s * 256;                        // 0..1023
      int kr = ch >> 4, kc = (ch & 15) ^ (kr & 7);   // K row 0..63, 16 chunks/row
      gl_lds16(kb + (size_t)(kt * 64 + kr) * QKVW + kc * 8, &lK[buf][ch * 8]);
      int vr = ch >> 3, vc = (ch & 7) ^ (vr & 7);    // V row 0..127, 8 chunks/row
      gl_lds16(vtb + (size_t)vr * T_ + kt * 64 + vc * 8, &lV[buf][ch * 8]);
    }
  };

  // softmax + PV for one q-tile's S-accumulator (QK^T already done; S is
  // pre-scaled via Q — values are already in exp2-ready log2 units)
  auto smpv = [&](f32x4* sacc, f32x4* oacc, float* mrow, float* lrow,
                  int jw, int kt, int cb) {
    if (kt == jw) {                            // diag tile: causal mask only
#pragma unroll
      for (int nj = 0; nj < 4; ++nj) {
        int key = nj * 16 + l15;               // local key 0..63
#pragma unroll
        for (int r = 0; r < 4; ++r) {
          int qrow = w * 16 + quad * 4 + r;    // local q 0..63
          if (key > qrow) sacc[nj][r] = -__builtin_inff();
        }
      }
    }
    // per-lane partial max + single ballot defer-check (T13)
    float pm[4];
#pragma unroll
    for (int r = 0; r < 4; ++r)
      pm[r] = fmaxf(fmaxf(sacc[0][r], sacc[1][r]), fmaxf(sacc[2][r], sacc[3][r]));
    float dmax = fmaxf(fmaxf(pm[0] - mrow[0], pm[1] - mrow[1]),
                       fmaxf(pm[2] - mrow[2], pm[3] - mrow[3]));
    if (__any(dmax > 11.5f)) {                 // rare: real max growth
#pragma unroll
      for (int r = 0; r < 4; ++r) {
        float rm = pm[r];
        rm = fmaxf(rm, __shfl_xor(rm, 1));
        rm = fmaxf(rm, __shfl_xor(rm, 2));
        rm = fmaxf(rm, __shfl_xor(rm, 4));
        rm = fmaxf(rm, __shfl_xor(rm, 8));
        float mold = mrow[r];
        float mnew = fmaxf(mold, rm);
        float alpha = exp2f(mold - mnew);
#pragma unroll
        for (int nd = 0; nd < 8; ++nd) oacc[nd][r] *= alpha;
        lrow[r] *= alpha;
        mrow[r] = mnew;
      }
    }
#pragma unroll
    for (int r = 0; r < 4; ++r) {
      int prow = w * 16 + quad * 4 + r;        // wave-private P row
      float rs = 0.f;
#pragma unroll
      for (int nj = 0; nj < 4; ++nj) {
        float p = exp2f(sacc[nj][r] - mrow[r]);
        rs += p;
        lP[prow * APW + nj * 16 + l15] = f2b(p);
      }
      lrow[r] += rs;                           // per-lane partial (no shfl)
    }
    // PV: O += P * V  (P rows wave-private — no barrier needed)
#pragma unroll
    for (int kk = 0; kk < 2; ++kk) {
      bf16x8 pf, vf[8];
      pf = *(const bf16x8*)&lP[(w * 16 + l15) * APW + kk * 32 + quad * 8];
#pragma unroll
      for (int nd = 0; nd < 8; ++nd) {
        int r = nd * 16 + l15;
        vf[nd] = *(const bf16x8*)&lV[cb][r * 64 + ((kk * 32 + quad * 8) ^ ((r & 7) << 3))];
      }
      __builtin_amdgcn_s_setprio(1);
#pragma unroll
      for (int nd = 0; nd < 8; ++nd)
        oacc[nd] = __builtin_amdgcn_mfma_f32_16x16x32_bf16(pf, vf[nd], oacc[nd], 0, 0, 0);
      __builtin_amdgcn_s_setprio(0);
    }
  };

  stage(0, 0);
  __syncthreads();   // drains vmcnt (implicit in __syncthreads)

  for (int kt = 0; kt <= jB; ++kt) {
    int cb = kt & 1;
    if (kt < jB) stage(kt + 1, cb ^ 1);       // overlap next-tile DMA with compute
    const bool doA = (kt <= jA);
    // QK^T for B (and A when paired) with a SINGLE kf load per kk
    f32x4 sB[4] = {}, sA[4] = {};
#pragma unroll
    for (int kk = 0; kk < 4; ++kk) {
      bf16x8 kf[4];
#pragma unroll
      for (int nj = 0; nj < 4; ++nj) {
        int r = nj * 16 + l15;
        kf[nj] = *(const bf16x8*)&lK[cb][r * 128 + ((kk * 32 + quad * 8) ^ ((r & 7) << 3))];
      }
      __builtin_amdgcn_s_setprio(1);
#pragma unroll
      for (int nj = 0; nj < 4; ++nj)
        sB[nj] = __builtin_amdgcn_mfma_f32_16x16x32_bf16(qfB[kk], kf[nj], sB[nj], 0, 0, 0);
      if (doA)
#pragma unroll
        for (int nj = 0; nj < 4; ++nj)
          sA[nj] = __builtin_amdgcn_mfma_f32_16x16x32_bf16(qfA[kk], kf[nj], sA[nj], 0, 0, 0);
      __builtin_amdgcn_s_setprio(0);
    }
    smpv(sB, oB, mB, lBr, jB, kt, cb);
    if (doA) smpv(sA, oA, mA, lAr, jA, kt, cb);
    __syncthreads();                          // drains stage DMA + LDS, swap bufs
  }

  // single cross-lane reduction of the per-lane l partials
#pragma unroll
  for (int r = 0; r < 4; ++r) {
    float sA = lAr[r], sB = lBr[r];
    sA += __shfl_xor(sA, 1); sB += __shfl_xor(sB, 1);
    sA += __shfl_xor(sA, 2); sB += __shfl_xor(sB, 2);
    sA += __shfl_xor(sA, 4); sB += __shfl_xor(sB, 4);
    sA += __shfl_xor(sA, 8); sB += __shfl_xor(sB, 8);
    lAr[r] = sA; lBr[r] = sB;
  }

  // epilogue: O / l -> bf16, REFERENCE-MATCHED layout [B*H][T][D] (see note)
#pragma unroll
  for (int nd = 0; nd < 8; ++nd)
#pragma unroll
    for (int r = 0; r < 4; ++r) {
      int dcol = nd * 16 + l15;
      int qrB = jB * 64 + w * 16 + quad * 4 + r;
      obuf[((size_t)bh * T_ + qrB) * D_ + dcol] = f2b(oB[nd][r] / lBr[r]);
      int qrA = jA * 64 + w * 16 + quad * 4 + r;
      obuf[((size_t)bh * T_ + qrA) * D_ + dcol] = f2b(oA[nd][r] / lAr[r]);
    }
}

extern "C" void kernel_launch(void* const* d_in, const int* in_sizes, int n_in,
                              void* d_out, int out_size, void* d_ws, size_t ws_size,
                              hipStream_t stream) {
  const float* x = (const float*)d_in[0];
  const float* Wqkv = (const float*)d_in[1];
  const float* Wout = (const float*)d_in[2];
  float* out = (float*)d_out;
  char* ws = (char*)d_ws;

  // workspace layout (bytes):
  //   [0,            16777216)  xb (x bf16)   -- later reused as Ob (attn out bf16)
  //   [16777216,     41943040)  Wqkv_t bf16   -- later reused as Wout_t bf16
  //   [41943040,     92274688)  qkv bf16 [4096][6144]
  //   [92274688,    109051904)  Vt bf16 [B*H][128][2048]
  u16* xb   = (u16*)ws;
  u16* wqt  = (u16*)(ws + 16777216);
  u16* qkvb = (u16*)(ws + 41943040);
  u16* vtb  = (u16*)(ws + 92274688);
  u16* wot  = wqt;   // alias: cast after GEMM1 consumed Wqkv_t
  u16* ob   = xb;    // alias: attn output after GEMM1 consumed xb

  castbf<<<4096, 256, 0, stream>>>(x, xb);                                  // 8.4M elems
  castT<<<dim3(96, 32), 256, 0, stream>>>(Wqkv, wqt, 2048, 6144);
  // gemm1 split into two exact rounds: 256 full tiles (n 0..15) + 256 half
  // tiles (n 16..23) -> makespan T + T/2 instead of 2T (384 @ 1 block/CU).
  gemm256<1><<<dim3(256), 512, 0, stream>>>(xb, wqt, qkvb, 4096, 6144, 2048, 16);
  gemmH<1><<<dim3(256), 512, 0, stream>>>(xb, wqt, qkvb, 4096, 6144, 2048, 8, 4096);
  castT<<<dim3(32, 32), 256, 0, stream>>>(Wout, wot, 2048, 2048);
  rope_k<<<4096, 256, 0, stream>>>(qkvb);
  vtrans<<<dim3(16, 32), 256, 0, stream>>>(qkvb, vtb);
  attn<<<dim3(32, 16), 256, 0, stream>>>(qkvb, vtb, ob);   // (bh, jpair)
  // gemm2 as 256 half-tiles: one exact round of half-duration blocks.
  gemmH<0><<<dim3(256), 512, 0, stream>>>(ob, wot, out, 4096, 2048, 2048, 8, 0);
}